// Round 1
// baseline (9939.491 us; speedup 1.0000x reference)
//
#include <hip/hip_runtime.h>

// ---------------------------------------------------------------------------
// GraphSAGE 3-layer forward, MI355X.
// Strategy:
//   1. Build CSR by dst (count -> exclusive scan -> fill with atomics).
//   2. Per layer: GEMM  yz = in @ [Wl;Wr].T (+b on z half)   [fp32, LDS tiled]
//      then gather-mean over in-edges (one wave per node, register acc),
//      fused +z, ReLU, LayerNorm epilogue (layers 0,1) or plain add (layer 2).
// No float atomics anywhere -> deterministic.
// ---------------------------------------------------------------------------

__global__ void count_deg(const int* __restrict__ dst, int* __restrict__ deg, int E) {
    int e = blockIdx.x * blockDim.x + threadIdx.x;
    if (e < E) atomicAdd(&deg[dst[e]], 1);
}

// Single-block exclusive scan over n entries. Writes offs[0..n] and turns
// deg_cursor[i] into the exclusive prefix (cursor for the fill pass).
__global__ __launch_bounds__(1024) void scan_deg(int* __restrict__ deg_cursor,
                                                 int* __restrict__ offs, int n) {
    __shared__ int sm[1024];
    __shared__ int s_running;
    int t = threadIdx.x;
    if (t == 0) s_running = 0;
    __syncthreads();
    for (int base = 0; base < n; base += 1024) {
        int i = base + t;
        int v = (i < n) ? deg_cursor[i] : 0;
        sm[t] = v;
        __syncthreads();
        for (int off = 1; off < 1024; off <<= 1) {
            int add = (t >= off) ? sm[t - off] : 0;
            __syncthreads();
            sm[t] += add;
            __syncthreads();
        }
        int incl = sm[t];
        int run = s_running;
        if (i < n) {
            int excl = run + incl - v;
            offs[i] = excl;
            deg_cursor[i] = excl;
        }
        __syncthreads();
        if (t == 1023) s_running = run + incl;
        __syncthreads();
    }
    if (t == 0) offs[n] = s_running;
}

__global__ void fill_csr(const int* __restrict__ src, const int* __restrict__ dst,
                         int* __restrict__ cursor, int* __restrict__ sorted_src, int E) {
    int e = blockIdx.x * blockDim.x + threadIdx.x;
    if (e < E) {
        int p = atomicAdd(&cursor[dst[e]], 1);
        sorted_src[p] = src[e];
    }
}

// ---------------------------------------------------------------------------
// GEMM: out[M][2*dout] = A[M][128] @ [Wl;Wr].T, +bias on the z (Wr) half.
// 64x64 tile, full K=128 resident in LDS, XOR bank swizzle (no padding):
// phys 4-float group = kgroup ^ (row & 7).  LDS = 2 * 32 KiB = 64 KiB.
// Thread (R=t>>4, C=t&15) computes rows {R+16i} x cols {C+16j}.
// ---------------------------------------------------------------------------
__global__ __launch_bounds__(256) void gemm_yz(
    const float* __restrict__ A,    // [M][128]
    const float* __restrict__ Wl,   // [dout][128]
    const float* __restrict__ Wr,   // [dout][128]
    const float* __restrict__ bias, // [dout]
    float* __restrict__ out,        // [M][2*dout]
    int M, int dout) {
    __shared__ float Asm[64 * 128];
    __shared__ float Bsm[64 * 128];

    const int t = threadIdx.x;
    const int rowBase = blockIdx.x * 64;
    const int gcolBase = blockIdx.y * 64;
    const bool isZ = (gcolBase >= dout);
    const float* W = isZ ? Wr : Wl;
    const int colLocal = gcolBase - (isZ ? dout : 0);

    // Stage A tile: 64 rows x 128 cols = 2048 float4, 8 per thread.
#pragma unroll
    for (int i = 0; i < 8; ++i) {
        int idx = t + 256 * i;
        int r = idx >> 5;          // 32 float4 per row
        int c4 = idx & 31;
        int grow = rowBase + r;
        if (grow >= M) grow = M - 1;   // clamp; stores are guarded
        float4 v = *(const float4*)(A + (size_t)grow * 128 + c4 * 4);
        int pg = c4 ^ (r & 7);
        *(float4*)(Asm + r * 128 + pg * 4) = v;
    }
    // Stage B tile: rows are W rows (= output cols of this block).
#pragma unroll
    for (int i = 0; i < 8; ++i) {
        int idx = t + 256 * i;
        int r = idx >> 5;
        int c4 = idx & 31;
        float4 v = *(const float4*)(W + (size_t)(colLocal + r) * 128 + c4 * 4);
        int pg = c4 ^ (r & 7);
        *(float4*)(Bsm + r * 128 + pg * 4) = v;
    }
    __syncthreads();

    const int R = t >> 4;   // 0..15 (0..3 within a wave)
    const int C = t & 15;   // 0..15 within a wave -> coalesced stores
    float acc[4][4] = {};

#pragma unroll
    for (int kg = 0; kg < 32; ++kg) {
        float4 a[4], b[4];
#pragma unroll
        for (int i = 0; i < 4; ++i) {
            int row = R + 16 * i;
            a[i] = *(const float4*)(Asm + row * 128 + ((kg ^ (row & 7)) << 2));
        }
#pragma unroll
        for (int j = 0; j < 4; ++j) {
            int col = C + 16 * j;
            b[j] = *(const float4*)(Bsm + col * 128 + ((kg ^ (col & 7)) << 2));
        }
#pragma unroll
        for (int i = 0; i < 4; ++i)
#pragma unroll
            for (int j = 0; j < 4; ++j)
                acc[i][j] += a[i].x * b[j].x + a[i].y * b[j].y +
                             a[i].z * b[j].z + a[i].w * b[j].w;
    }

    const int ld = 2 * dout;
#pragma unroll
    for (int i = 0; i < 4; ++i) {
        int row = rowBase + R + 16 * i;
        if (row >= M) continue;
#pragma unroll
        for (int j = 0; j < 4; ++j) {
            int col = C + 16 * j;
            float v = acc[i][j];
            if (isZ) v += bias[colLocal + col];
            out[(size_t)row * ld + gcolBase + col] = v;
        }
    }
}

// ---------------------------------------------------------------------------
// Aggregation, 128 features: one wave per node. Gather mean of y rows
// (yz cols 0..127), add z (cols 128..255), ReLU, LayerNorm -> hout.
// ---------------------------------------------------------------------------
__global__ __launch_bounds__(256) void agg_ln128(
    const int* __restrict__ offs, const int* __restrict__ ssrc,
    const float* __restrict__ yz,    // [N][256]
    const float* __restrict__ gamma, const float* __restrict__ beta,
    float* __restrict__ hout, int nNodes) {
    int lane = threadIdx.x & 63;
    int node = blockIdx.x * 4 + (threadIdx.x >> 6);
    if (node >= nNodes) return;
    int beg = offs[node], end = offs[node + 1];

    float2 acc = make_float2(0.f, 0.f);
    for (int j = beg; j < end; j += 64) {
        int cnt = end - j;
        if (cnt > 64) cnt = 64;
        int sidx = ssrc[j + ((lane < cnt) ? lane : 0)];
        for (int u = 0; u < cnt; ++u) {
            int s = __shfl(sidx, u, 64);
            float2 v = *(const float2*)(yz + (size_t)s * 256 + lane * 2);
            acc.x += v.x;
            acc.y += v.y;
        }
    }
    int degn = end - beg;
    float inv = 1.f / (float)((degn > 1) ? degn : 1);
    float2 z = *(const float2*)(yz + (size_t)node * 256 + 128 + lane * 2);
    float vx = fmaxf(acc.x * inv + z.x, 0.f);
    float vy = fmaxf(acc.y * inv + z.y, 0.f);

    float s = vx + vy;
#pragma unroll
    for (int off = 32; off >= 1; off >>= 1) s += __shfl_xor(s, off, 64);
    float mu = s * (1.f / 128.f);
    float dx = vx - mu, dy = vy - mu;
    float q = dx * dx + dy * dy;
#pragma unroll
    for (int off = 32; off >= 1; off >>= 1) q += __shfl_xor(q, off, 64);
    float rstd = rsqrtf(q * (1.f / 128.f) + 1e-5f);

    float2 gg = *(const float2*)(gamma + lane * 2);
    float2 bb = *(const float2*)(beta + lane * 2);
    float2 o = make_float2(dx * rstd * gg.x + bb.x, dy * rstd * gg.y + bb.y);
    *(float2*)(hout + (size_t)node * 128 + lane * 2) = o;
}

// Aggregation, 64 features (final layer): mean(y2) + z2 -> out. No LN/ReLU.
__global__ __launch_bounds__(256) void agg_out64(
    const int* __restrict__ offs, const int* __restrict__ ssrc,
    const float* __restrict__ yz,    // [N][128]: y2 0..63, z2 64..127
    float* __restrict__ out, int nNodes) {
    int lane = threadIdx.x & 63;
    int node = blockIdx.x * 4 + (threadIdx.x >> 6);
    if (node >= nNodes) return;
    int beg = offs[node], end = offs[node + 1];

    float acc = 0.f;
    for (int j = beg; j < end; j += 64) {
        int cnt = end - j;
        if (cnt > 64) cnt = 64;
        int sidx = ssrc[j + ((lane < cnt) ? lane : 0)];
        for (int u = 0; u < cnt; ++u) {
            int s = __shfl(sidx, u, 64);
            acc += yz[(size_t)s * 128 + lane];
        }
    }
    int degn = end - beg;
    float inv = 1.f / (float)((degn > 1) ? degn : 1);
    out[(size_t)node * 64 + lane] = acc * inv + yz[(size_t)node * 128 + 64 + lane];
}

// ---------------------------------------------------------------------------
extern "C" void kernel_launch(void* const* d_in, const int* in_sizes, int n_in,
                              void* d_out, int out_size, void* d_ws, size_t ws_size,
                              hipStream_t stream) {
    const float* x   = (const float*)d_in[0];
    const int*   ei  = (const int*)d_in[1];
    const float* Wl0 = (const float*)d_in[2];
    const float* Wr0 = (const float*)d_in[3];
    const float* b0  = (const float*)d_in[4];
    const float* Wl1 = (const float*)d_in[5];
    const float* Wr1 = (const float*)d_in[6];
    const float* b1  = (const float*)d_in[7];
    const float* Wl2 = (const float*)d_in[8];
    const float* Wr2 = (const float*)d_in[9];
    const float* b2  = (const float*)d_in[10];
    const float* g0  = (const float*)d_in[11];
    const float* be0 = (const float*)d_in[12];
    const float* g1  = (const float*)d_in[13];
    const float* be1 = (const float*)d_in[14];

    const int N = in_sizes[0] / 128;
    const int E = in_sizes[1] / 2;
    const int* src = ei;
    const int* dst = ei + E;
    float* out = (float*)d_out;

    char* p = (char*)d_ws;
    auto carve = [&](size_t bytes) {
        void* q = (void*)p;
        p += (bytes + 255) & ~(size_t)255;
        return q;
    };
    int*   offs = (int*)carve(sizeof(int) * (size_t)(N + 1));
    int*   degc = (int*)carve(sizeof(int) * (size_t)N);
    int*   ssrc = (int*)carve(sizeof(int) * (size_t)E);
    float* yz   = (float*)carve(sizeof(float) * (size_t)N * 256);
    float* h    = (float*)carve(sizeof(float) * (size_t)N * 128);

    // --- CSR build (reused by all 3 layers) ---
    hipMemsetAsync(degc, 0, sizeof(int) * (size_t)N, stream);
    count_deg<<<(E + 255) / 256, 256, 0, stream>>>(dst, degc, E);
    scan_deg<<<1, 1024, 0, stream>>>(degc, offs, N);
    fill_csr<<<(E + 255) / 256, 256, 0, stream>>>(src, dst, degc, ssrc, E);

    const int gridM = (N + 63) / 64;
    const int gridNode = (N + 3) / 4;

    // --- Layer 0 ---
    gemm_yz<<<dim3(gridM, 4), 256, 0, stream>>>(x, Wl0, Wr0, b0, yz, N, 128);
    agg_ln128<<<gridNode, 256, 0, stream>>>(offs, ssrc, yz, g0, be0, h, N);
    // --- Layer 1 ---
    gemm_yz<<<dim3(gridM, 4), 256, 0, stream>>>(h, Wl1, Wr1, b1, yz, N, 128);
    agg_ln128<<<gridNode, 256, 0, stream>>>(offs, ssrc, yz, g1, be1, h, N);
    // --- Layer 2 (outputs 64 feats, no LN/ReLU) ---
    gemm_yz<<<dim3(gridM, 2), 256, 0, stream>>>(h, Wl2, Wr2, b2, yz, N, 64);
    agg_out64<<<gridNode, 256, 0, stream>>>(offs, ssrc, yz, out, N);
}

// Round 2
// 1113.880 us; speedup vs baseline: 8.9233x; 8.9233x over previous
//
#include <hip/hip_runtime.h>

// ---------------------------------------------------------------------------
// GraphSAGE 3-layer forward, MI355X.
//   1. Build CSR by dst (count -> exclusive scan -> fill with atomics).
//   2. Per layer: GEMM  yz = in @ [Wl;Wr].T (+b on z half)   [fp32, LDS tiled]
//      then gather-mean over in-edges (one wave per node, register acc),
//      fused +z, ReLU, LayerNorm epilogue (layers 0,1) or plain add (layer 2).
// R1 fix: GEMM rewritten — capped unroll (no spills), +4 padding (132-float
// stride, 2-way-max LDS aliasing = free), hoisted base pointers.
// ---------------------------------------------------------------------------

__global__ void count_deg(const int* __restrict__ dst, int* __restrict__ deg, int E) {
    int e = blockIdx.x * blockDim.x + threadIdx.x;
    if (e < E) atomicAdd(&deg[dst[e]], 1);
}

__global__ __launch_bounds__(1024) void scan_deg(int* __restrict__ deg_cursor,
                                                 int* __restrict__ offs, int n) {
    __shared__ int sm[1024];
    __shared__ int s_running;
    int t = threadIdx.x;
    if (t == 0) s_running = 0;
    __syncthreads();
    for (int base = 0; base < n; base += 1024) {
        int i = base + t;
        int v = (i < n) ? deg_cursor[i] : 0;
        sm[t] = v;
        __syncthreads();
        for (int off = 1; off < 1024; off <<= 1) {
            int add = (t >= off) ? sm[t - off] : 0;
            __syncthreads();
            sm[t] += add;
            __syncthreads();
        }
        int incl = sm[t];
        int run = s_running;
        if (i < n) {
            int excl = run + incl - v;
            offs[i] = excl;
            deg_cursor[i] = excl;
        }
        __syncthreads();
        if (t == 1023) s_running = run + incl;
        __syncthreads();
    }
    if (t == 0) offs[n] = s_running;
}

__global__ void fill_csr(const int* __restrict__ src, const int* __restrict__ dst,
                         int* __restrict__ cursor, int* __restrict__ sorted_src, int E) {
    int e = blockIdx.x * blockDim.x + threadIdx.x;
    if (e < E) {
        int p = atomicAdd(&cursor[dst[e]], 1);
        sorted_src[p] = src[e];
    }
}

// ---------------------------------------------------------------------------
// GEMM: out[M][2*dout] = A[M][128] @ [Wl;Wr].T, +bias on the z (Wr) half.
// 64x64 tile, full K=128 in LDS with +4-float pad (stride 132; float4 stays
// 16B-aligned; worst LDS aliasing is 2-way = free). 256 threads; thread
// (R=t>>4, C=t&15) computes rows 4R..4R+3 x cols {C+16j}.
// K-loop: #pragma unroll 4 — capping unroll keeps VGPRs low (R1: full unroll
// hit the 256-VGPR cap and spilled 9 GB to scratch).
// ---------------------------------------------------------------------------
__global__ __launch_bounds__(256) void gemm_yz(
    const float* __restrict__ A,    // [M][128]
    const float* __restrict__ Wl,   // [dout][128]
    const float* __restrict__ Wr,   // [dout][128]
    const float* __restrict__ bias, // [dout]
    float* __restrict__ out,        // [M][2*dout]
    int M, int dout) {
    __shared__ float Asm[64 * 132];
    __shared__ float Bsm[64 * 132];

    const int t = threadIdx.x;
    const int rowBase = blockIdx.x * 64;
    const int gcolBase = blockIdx.y * 64;
    const bool isZ = (gcolBase >= dout);
    const float* W = isZ ? Wr : Wl;
    const int colLocal = gcolBase - (isZ ? dout : 0);

    // Stage A tile: 64 rows x 128 cols = 2048 float4, 8 per thread, coalesced.
#pragma unroll
    for (int i = 0; i < 8; ++i) {
        int idx = t + 256 * i;
        int r = idx >> 5;          // 32 float4 per row
        int c4 = idx & 31;
        int grow = rowBase + r;
        if (grow >= M) grow = M - 1;   // clamp; stores are guarded
        float4 v = *(const float4*)(A + (size_t)grow * 128 + c4 * 4);
        *(float4*)(Asm + r * 132 + c4 * 4) = v;
    }
    // Stage B tile: rows are W rows (= output cols of this block).
#pragma unroll
    for (int i = 0; i < 8; ++i) {
        int idx = t + 256 * i;
        int r = idx >> 5;
        int c4 = idx & 31;
        float4 v = *(const float4*)(W + (size_t)(colLocal + r) * 128 + c4 * 4);
        *(float4*)(Bsm + r * 132 + c4 * 4) = v;
    }
    __syncthreads();

    const int R = t >> 4;   // 0..15
    const int C = t & 15;   // 0..15
    const float* Ap = Asm + R * 4 * 132;
    const float* Bp = Bsm + C * 132;
    float acc[4][4] = {};

#pragma unroll 4
    for (int kg = 0; kg < 32; ++kg) {
        float4 a[4], b[4];
#pragma unroll
        for (int i = 0; i < 4; ++i)
            a[i] = *(const float4*)(Ap + i * 132 + kg * 4);
#pragma unroll
        for (int j = 0; j < 4; ++j)
            b[j] = *(const float4*)(Bp + j * 16 * 132 + kg * 4);
#pragma unroll
        for (int i = 0; i < 4; ++i)
#pragma unroll
            for (int j = 0; j < 4; ++j)
                acc[i][j] += a[i].x * b[j].x + a[i].y * b[j].y +
                             a[i].z * b[j].z + a[i].w * b[j].w;
    }

    const int ld = 2 * dout;
#pragma unroll
    for (int i = 0; i < 4; ++i) {
        int row = rowBase + R * 4 + i;
        if (row >= M) continue;
#pragma unroll
        for (int j = 0; j < 4; ++j) {
            int col = C + 16 * j;
            float v = acc[i][j];
            if (isZ) v += bias[colLocal + col];
            out[(size_t)row * ld + gcolBase + col] = v;
        }
    }
}

// ---------------------------------------------------------------------------
// Aggregation, 128 features: one wave per node. Gather mean of y rows
// (yz cols 0..127), add z (cols 128..255), ReLU, LayerNorm -> hout.
// ---------------------------------------------------------------------------
__global__ __launch_bounds__(256) void agg_ln128(
    const int* __restrict__ offs, const int* __restrict__ ssrc,
    const float* __restrict__ yz,    // [N][256]
    const float* __restrict__ gamma, const float* __restrict__ beta,
    float* __restrict__ hout, int nNodes) {
    int lane = threadIdx.x & 63;
    int node = blockIdx.x * 4 + (threadIdx.x >> 6);
    if (node >= nNodes) return;
    int beg = offs[node], end = offs[node + 1];

    float2 acc = make_float2(0.f, 0.f);
    for (int j = beg; j < end; j += 64) {
        int cnt = end - j;
        if (cnt > 64) cnt = 64;
        int sidx = ssrc[j + ((lane < cnt) ? lane : 0)];
        for (int u = 0; u < cnt; ++u) {
            int s = __shfl(sidx, u, 64);
            float2 v = *(const float2*)(yz + (size_t)s * 256 + lane * 2);
            acc.x += v.x;
            acc.y += v.y;
        }
    }
    int degn = end - beg;
    float inv = 1.f / (float)((degn > 1) ? degn : 1);
    float2 z = *(const float2*)(yz + (size_t)node * 256 + 128 + lane * 2);
    float vx = fmaxf(acc.x * inv + z.x, 0.f);
    float vy = fmaxf(acc.y * inv + z.y, 0.f);

    float s = vx + vy;
#pragma unroll
    for (int off = 32; off >= 1; off >>= 1) s += __shfl_xor(s, off, 64);
    float mu = s * (1.f / 128.f);
    float dx = vx - mu, dy = vy - mu;
    float q = dx * dx + dy * dy;
#pragma unroll
    for (int off = 32; off >= 1; off >>= 1) q += __shfl_xor(q, off, 64);
    float rstd = rsqrtf(q * (1.f / 128.f) + 1e-5f);

    float2 gg = *(const float2*)(gamma + lane * 2);
    float2 bb = *(const float2*)(beta + lane * 2);
    float2 o = make_float2(dx * rstd * gg.x + bb.x, dy * rstd * gg.y + bb.y);
    *(float2*)(hout + (size_t)node * 128 + lane * 2) = o;
}

// Aggregation, 64 features (final layer): mean(y2) + z2 -> out. No LN/ReLU.
__global__ __launch_bounds__(256) void agg_out64(
    const int* __restrict__ offs, const int* __restrict__ ssrc,
    const float* __restrict__ yz,    // [N][128]: y2 0..63, z2 64..127
    float* __restrict__ out, int nNodes) {
    int lane = threadIdx.x & 63;
    int node = blockIdx.x * 4 + (threadIdx.x >> 6);
    if (node >= nNodes) return;
    int beg = offs[node], end = offs[node + 1];

    float acc = 0.f;
    for (int j = beg; j < end; j += 64) {
        int cnt = end - j;
        if (cnt > 64) cnt = 64;
        int sidx = ssrc[j + ((lane < cnt) ? lane : 0)];
        for (int u = 0; u < cnt; ++u) {
            int s = __shfl(sidx, u, 64);
            acc += yz[(size_t)s * 128 + lane];
        }
    }
    int degn = end - beg;
    float inv = 1.f / (float)((degn > 1) ? degn : 1);
    out[(size_t)node * 64 + lane] = acc * inv + yz[(size_t)node * 128 + 64 + lane];
}

// ---------------------------------------------------------------------------
extern "C" void kernel_launch(void* const* d_in, const int* in_sizes, int n_in,
                              void* d_out, int out_size, void* d_ws, size_t ws_size,
                              hipStream_t stream) {
    const float* x   = (const float*)d_in[0];
    const int*   ei  = (const int*)d_in[1];
    const float* Wl0 = (const float*)d_in[2];
    const float* Wr0 = (const float*)d_in[3];
    const float* b0  = (const float*)d_in[4];
    const float* Wl1 = (const float*)d_in[5];
    const float* Wr1 = (const float*)d_in[6];
    const float* b1  = (const float*)d_in[7];
    const float* Wl2 = (const float*)d_in[8];
    const float* Wr2 = (const float*)d_in[9];
    const float* b2  = (const float*)d_in[10];
    const float* g0  = (const float*)d_in[11];
    const float* be0 = (const float*)d_in[12];
    const float* g1  = (const float*)d_in[13];
    const float* be1 = (const float*)d_in[14];

    const int N = in_sizes[0] / 128;
    const int E = in_sizes[1] / 2;
    const int* src = ei;
    const int* dst = ei + E;
    float* out = (float*)d_out;

    char* p = (char*)d_ws;
    auto carve = [&](size_t bytes) {
        void* q = (void*)p;
        p += (bytes + 255) & ~(size_t)255;
        return q;
    };
    int*   offs = (int*)carve(sizeof(int) * (size_t)(N + 1));
    int*   degc = (int*)carve(sizeof(int) * (size_t)N);
    int*   ssrc = (int*)carve(sizeof(int) * (size_t)E);
    float* yz   = (float*)carve(sizeof(float) * (size_t)N * 256);
    float* h    = (float*)carve(sizeof(float) * (size_t)N * 128);

    // --- CSR build (reused by all 3 layers) ---
    hipMemsetAsync(degc, 0, sizeof(int) * (size_t)N, stream);
    count_deg<<<(E + 255) / 256, 256, 0, stream>>>(dst, degc, E);
    scan_deg<<<1, 1024, 0, stream>>>(degc, offs, N);
    fill_csr<<<(E + 255) / 256, 256, 0, stream>>>(src, dst, degc, ssrc, E);

    const int gridM = (N + 63) / 64;
    const int gridNode = (N + 3) / 4;

    // --- Layer 0 ---
    gemm_yz<<<dim3(gridM, 4), 256, 0, stream>>>(x, Wl0, Wr0, b0, yz, N, 128);
    agg_ln128<<<gridNode, 256, 0, stream>>>(offs, ssrc, yz, g0, be0, h, N);
    // --- Layer 1 ---
    gemm_yz<<<dim3(gridM, 4), 256, 0, stream>>>(h, Wl1, Wr1, b1, yz, N, 128);
    agg_ln128<<<gridNode, 256, 0, stream>>>(offs, ssrc, yz, g1, be1, h, N);
    // --- Layer 2 (outputs 64 feats, no LN/ReLU) ---
    gemm_yz<<<dim3(gridM, 2), 256, 0, stream>>>(h, Wl2, Wr2, b2, yz, N, 64);
    agg_out64<<<gridNode, 256, 0, stream>>>(offs, ssrc, yz, out, N);
}

// Round 3
// 899.658 us; speedup vs baseline: 11.0481x; 1.2381x over previous
//
#include <hip/hip_runtime.h>

// ---------------------------------------------------------------------------
// GraphSAGE 3-layer forward, MI355X.
//   1. Build CSR by dst (count -> hierarchical 3-pass scan -> fill w/ atomics).
//   2. Per layer: GEMM  yz = in @ [Wl;Wr].T (+b on z half)   [fp32, LDS tiled]
//      then gather-mean over in-edges (waves gather 2-4 edge rows/iter via
//      float4), fused +z, ReLU, LayerNorm epilogue (layers 0,1) or add (l2).
// R2 fix: single-block scan (183 us, 0.2% occupancy) -> 3-pass parallel scan.
//         agg kernels: float4 gathers, 2 (128f) / 4 (64f) edges per wave iter.
// ---------------------------------------------------------------------------

__global__ void count_deg(const int* __restrict__ dst, int* __restrict__ deg, int E) {
    int e = blockIdx.x * blockDim.x + threadIdx.x;
    if (e < E) atomicAdd(&deg[dst[e]], 1);
}

#define SB 256
#define SE 4096  // elements scanned per block (16 per thread)

__global__ __launch_bounds__(SB) void scan_block_sums(const int* __restrict__ deg,
                                                      int* __restrict__ bsums, int n) {
    __shared__ int red[SB / 64];
    int t = threadIdx.x;
    int base = blockIdx.x * SE + t * 16;
    int s = 0;
#pragma unroll
    for (int i = 0; i < 16; ++i) {
        int idx = base + i;
        if (idx < n) s += deg[idx];
    }
#pragma unroll
    for (int off = 32; off >= 1; off >>= 1) s += __shfl_xor(s, off, 64);
    if ((t & 63) == 0) red[t >> 6] = s;
    __syncthreads();
    if (t == 0) {
        int tot = 0;
#pragma unroll
        for (int w = 0; w < SB / 64; ++w) tot += red[w];
        bsums[blockIdx.x] = tot;
    }
}

// Single small block: exclusive-scan the (<=1024) block sums; writes offs[n]=total.
__global__ __launch_bounds__(1024) void scan_partials(int* __restrict__ bsums,
                                                      int* __restrict__ offs,
                                                      int nb, int n) {
    __shared__ int sm[1024];
    int t = threadIdx.x;
    int v = (t < nb) ? bsums[t] : 0;
    sm[t] = v;
    __syncthreads();
    for (int off = 1; off < 1024; off <<= 1) {
        int add = (t >= off) ? sm[t - off] : 0;
        __syncthreads();
        sm[t] += add;
        __syncthreads();
    }
    if (t < nb) bsums[t] = sm[t] - v;   // exclusive
    if (t == 1023) offs[n] = sm[1023];  // grand total
}

__global__ __launch_bounds__(SB) void scan_final(int* __restrict__ degc,
                                                 const int* __restrict__ bsums,
                                                 int* __restrict__ offs, int n) {
    __shared__ int tsum[SB];
    int t = threadIdx.x;
    int base = blockIdx.x * SE + t * 16;
    int vals[16];
    int s = 0;
#pragma unroll
    for (int i = 0; i < 16; ++i) {
        int idx = base + i;
        vals[i] = (idx < n) ? degc[idx] : 0;
        s += vals[i];
    }
    tsum[t] = s;
    __syncthreads();
    for (int off = 1; off < SB; off <<= 1) {
        int add = (t >= off) ? tsum[t - off] : 0;
        __syncthreads();
        tsum[t] += add;
        __syncthreads();
    }
    int run = bsums[blockIdx.x] + tsum[t] - s;
#pragma unroll
    for (int i = 0; i < 16; ++i) {
        int idx = base + i;
        if (idx < n) {
            offs[idx] = run;
            degc[idx] = run;  // cursor for fill pass
            run += vals[i];
        }
    }
}

__global__ void fill_csr(const int* __restrict__ src, const int* __restrict__ dst,
                         int* __restrict__ cursor, int* __restrict__ sorted_src, int E) {
    int e = blockIdx.x * blockDim.x + threadIdx.x;
    if (e < E) {
        int p = atomicAdd(&cursor[dst[e]], 1);
        sorted_src[p] = src[e];
    }
}

// ---------------------------------------------------------------------------
// GEMM: out[M][2*dout] = A[M][128] @ [Wl;Wr].T, +bias on the z (Wr) half.
// 64x64 tile, full K=128 in LDS with +4-float pad (stride 132). 256 threads;
// thread (R=t>>4, C=t&15) computes rows 4R..4R+3 x cols {C+16j}.
// #pragma unroll 4 keeps VGPRs below the spill cliff (R1 lesson).
// ---------------------------------------------------------------------------
__global__ __launch_bounds__(256) void gemm_yz(
    const float* __restrict__ A,    // [M][128]
    const float* __restrict__ Wl,   // [dout][128]
    const float* __restrict__ Wr,   // [dout][128]
    const float* __restrict__ bias, // [dout]
    float* __restrict__ out,        // [M][2*dout]
    int M, int dout) {
    __shared__ float Asm[64 * 132];
    __shared__ float Bsm[64 * 132];

    const int t = threadIdx.x;
    const int rowBase = blockIdx.x * 64;
    const int gcolBase = blockIdx.y * 64;
    const bool isZ = (gcolBase >= dout);
    const float* W = isZ ? Wr : Wl;
    const int colLocal = gcolBase - (isZ ? dout : 0);

#pragma unroll
    for (int i = 0; i < 8; ++i) {
        int idx = t + 256 * i;
        int r = idx >> 5;
        int c4 = idx & 31;
        int grow = rowBase + r;
        if (grow >= M) grow = M - 1;
        float4 v = *(const float4*)(A + (size_t)grow * 128 + c4 * 4);
        *(float4*)(Asm + r * 132 + c4 * 4) = v;
    }
#pragma unroll
    for (int i = 0; i < 8; ++i) {
        int idx = t + 256 * i;
        int r = idx >> 5;
        int c4 = idx & 31;
        float4 v = *(const float4*)(W + (size_t)(colLocal + r) * 128 + c4 * 4);
        *(float4*)(Bsm + r * 132 + c4 * 4) = v;
    }
    __syncthreads();

    const int R = t >> 4;
    const int C = t & 15;
    const float* Ap = Asm + R * 4 * 132;
    const float* Bp = Bsm + C * 132;
    float acc[4][4] = {};

#pragma unroll 4
    for (int kg = 0; kg < 32; ++kg) {
        float4 a[4], b[4];
#pragma unroll
        for (int i = 0; i < 4; ++i)
            a[i] = *(const float4*)(Ap + i * 132 + kg * 4);
#pragma unroll
        for (int j = 0; j < 4; ++j)
            b[j] = *(const float4*)(Bp + j * 16 * 132 + kg * 4);
#pragma unroll
        for (int i = 0; i < 4; ++i)
#pragma unroll
            for (int j = 0; j < 4; ++j)
                acc[i][j] += a[i].x * b[j].x + a[i].y * b[j].y +
                             a[i].z * b[j].z + a[i].w * b[j].w;
    }

    const int ld = 2 * dout;
#pragma unroll
    for (int i = 0; i < 4; ++i) {
        int row = rowBase + R * 4 + i;
        if (row >= M) continue;
#pragma unroll
        for (int j = 0; j < 4; ++j) {
            int col = C + 16 * j;
            float v = acc[i][j];
            if (isZ) v += bias[colLocal + col];
            out[(size_t)row * ld + gcolBase + col] = v;
        }
    }
}

// ---------------------------------------------------------------------------
// Aggregation, 128 features: one wave per node, float4 gathers, 2 edge rows
// per iteration (lane halves). Fused mean + z + ReLU + LayerNorm.
// yz row = 256 floats = 64 float4: y = [0,32), z = [32,64).
// ---------------------------------------------------------------------------
__global__ __launch_bounds__(256) void agg_ln128(
    const int* __restrict__ offs, const int* __restrict__ ssrc,
    const float* __restrict__ yz,
    const float* __restrict__ gamma, const float* __restrict__ beta,
    float* __restrict__ hout, int nNodes) {
    const int lane = threadIdx.x & 63;
    const int half = lane >> 5;   // 0,1: which edge of the pair
    const int li   = lane & 31;   // float4 index within the row
    const int node = blockIdx.x * 4 + (threadIdx.x >> 6);
    if (node >= nNodes) return;
    const int beg = offs[node], end = offs[node + 1];
    const float4* yz4 = (const float4*)yz;

    float4 acc = make_float4(0.f, 0.f, 0.f, 0.f);
    for (int j = beg; j < end; j += 64) {
        int cnt = end - j;
        if (cnt > 64) cnt = 64;
        int sidx = ssrc[j + ((lane < cnt) ? lane : 0)];
        int pairs = (cnt + 1) >> 1;
        for (int u = 0; u < pairs; ++u) {
            int e = 2 * u + half;
            int s = __shfl(sidx, (e < cnt) ? e : 0, 64);
            if (e < cnt) {
                float4 v = yz4[(size_t)s * 64 + li];
                acc.x += v.x; acc.y += v.y; acc.z += v.z; acc.w += v.w;
            }
        }
    }
    // merge the two halves (each covers a disjoint edge subset, same features)
    acc.x += __shfl_xor(acc.x, 32, 64);
    acc.y += __shfl_xor(acc.y, 32, 64);
    acc.z += __shfl_xor(acc.z, 32, 64);
    acc.w += __shfl_xor(acc.w, 32, 64);

    int degn = end - beg;
    float inv = 1.f / (float)((degn > 1) ? degn : 1);
    float4 z = yz4[(size_t)node * 64 + 32 + li];
    float4 v;
    v.x = fmaxf(acc.x * inv + z.x, 0.f);
    v.y = fmaxf(acc.y * inv + z.y, 0.f);
    v.z = fmaxf(acc.z * inv + z.z, 0.f);
    v.w = fmaxf(acc.w * inv + z.w, 0.f);

    // LN over 128 feats; each 32-lane half holds full coverage -> butterfly
    // within 32 lanes (offsets 16..1).
    float s = v.x + v.y + v.z + v.w;
#pragma unroll
    for (int off = 16; off >= 1; off >>= 1) s += __shfl_xor(s, off, 64);
    float mu = s * (1.f / 128.f);
    float4 d = make_float4(v.x - mu, v.y - mu, v.z - mu, v.w - mu);
    float q = d.x * d.x + d.y * d.y + d.z * d.z + d.w * d.w;
#pragma unroll
    for (int off = 16; off >= 1; off >>= 1) q += __shfl_xor(q, off, 64);
    float rstd = rsqrtf(q * (1.f / 128.f) + 1e-5f);

    if (half == 0) {
        float4 g = ((const float4*)gamma)[li];
        float4 b = ((const float4*)beta)[li];
        float4 o;
        o.x = d.x * rstd * g.x + b.x;
        o.y = d.y * rstd * g.y + b.y;
        o.z = d.z * rstd * g.z + b.z;
        o.w = d.w * rstd * g.w + b.w;
        ((float4*)hout)[(size_t)node * 32 + li] = o;
    }
}

// Aggregation, 64 features (final layer): float4, 4 edge rows per iteration.
// yz row = 128 floats = 32 float4: y2 = [0,16), z2 = [16,32).
__global__ __launch_bounds__(256) void agg_out64(
    const int* __restrict__ offs, const int* __restrict__ ssrc,
    const float* __restrict__ yz,
    float* __restrict__ out, int nNodes) {
    const int lane = threadIdx.x & 63;
    const int qh = lane >> 4;   // 0..3: which edge of the quad
    const int li = lane & 15;   // float4 index within the row
    const int node = blockIdx.x * 4 + (threadIdx.x >> 6);
    if (node >= nNodes) return;
    const int beg = offs[node], end = offs[node + 1];
    const float4* yz4 = (const float4*)yz;

    float4 acc = make_float4(0.f, 0.f, 0.f, 0.f);
    for (int j = beg; j < end; j += 64) {
        int cnt = end - j;
        if (cnt > 64) cnt = 64;
        int sidx = ssrc[j + ((lane < cnt) ? lane : 0)];
        int quads = (cnt + 3) >> 2;
        for (int u = 0; u < quads; ++u) {
            int e = 4 * u + qh;
            int s = __shfl(sidx, (e < cnt) ? e : 0, 64);
            if (e < cnt) {
                float4 v = yz4[(size_t)s * 32 + li];
                acc.x += v.x; acc.y += v.y; acc.z += v.z; acc.w += v.w;
            }
        }
    }
    acc.x += __shfl_xor(acc.x, 16, 64); acc.x += __shfl_xor(acc.x, 32, 64);
    acc.y += __shfl_xor(acc.y, 16, 64); acc.y += __shfl_xor(acc.y, 32, 64);
    acc.z += __shfl_xor(acc.z, 16, 64); acc.z += __shfl_xor(acc.z, 32, 64);
    acc.w += __shfl_xor(acc.w, 16, 64); acc.w += __shfl_xor(acc.w, 32, 64);

    if (qh == 0) {
        int degn = end - beg;
        float inv = 1.f / (float)((degn > 1) ? degn : 1);
        float4 z = yz4[(size_t)node * 32 + 16 + li];
        float4 o;
        o.x = acc.x * inv + z.x;
        o.y = acc.y * inv + z.y;
        o.z = acc.z * inv + z.z;
        o.w = acc.w * inv + z.w;
        ((float4*)out)[(size_t)node * 16 + li] = o;
    }
}

// ---------------------------------------------------------------------------
extern "C" void kernel_launch(void* const* d_in, const int* in_sizes, int n_in,
                              void* d_out, int out_size, void* d_ws, size_t ws_size,
                              hipStream_t stream) {
    const float* x   = (const float*)d_in[0];
    const int*   ei  = (const int*)d_in[1];
    const float* Wl0 = (const float*)d_in[2];
    const float* Wr0 = (const float*)d_in[3];
    const float* b0  = (const float*)d_in[4];
    const float* Wl1 = (const float*)d_in[5];
    const float* Wr1 = (const float*)d_in[6];
    const float* b1  = (const float*)d_in[7];
    const float* Wl2 = (const float*)d_in[8];
    const float* Wr2 = (const float*)d_in[9];
    const float* b2  = (const float*)d_in[10];
    const float* g0  = (const float*)d_in[11];
    const float* be0 = (const float*)d_in[12];
    const float* g1  = (const float*)d_in[13];
    const float* be1 = (const float*)d_in[14];

    const int N = in_sizes[0] / 128;
    const int E = in_sizes[1] / 2;
    const int* src = ei;
    const int* dst = ei + E;
    float* out = (float*)d_out;

    char* p = (char*)d_ws;
    auto carve = [&](size_t bytes) {
        void* q = (void*)p;
        p += (bytes + 255) & ~(size_t)255;
        return q;
    };
    const int nb = (N + SE - 1) / SE;
    int*   offs  = (int*)carve(sizeof(int) * (size_t)(N + 1));
    int*   degc  = (int*)carve(sizeof(int) * (size_t)N);
    int*   bsums = (int*)carve(sizeof(int) * (size_t)nb);
    int*   ssrc  = (int*)carve(sizeof(int) * (size_t)E);
    float* yz    = (float*)carve(sizeof(float) * (size_t)N * 256);
    float* h     = (float*)carve(sizeof(float) * (size_t)N * 128);

    // --- CSR build (reused by all 3 layers) ---
    hipMemsetAsync(degc, 0, sizeof(int) * (size_t)N, stream);
    count_deg<<<(E + 255) / 256, 256, 0, stream>>>(dst, degc, E);
    scan_block_sums<<<nb, SB, 0, stream>>>(degc, bsums, N);
    scan_partials<<<1, 1024, 0, stream>>>(bsums, offs, nb, N);
    scan_final<<<nb, SB, 0, stream>>>(degc, bsums, offs, N);
    fill_csr<<<(E + 255) / 256, 256, 0, stream>>>(src, dst, degc, ssrc, E);

    const int gridM = (N + 63) / 64;
    const int gridNode = (N + 3) / 4;

    // --- Layer 0 ---
    gemm_yz<<<dim3(gridM, 4), 256, 0, stream>>>(x, Wl0, Wr0, b0, yz, N, 128);
    agg_ln128<<<gridNode, 256, 0, stream>>>(offs, ssrc, yz, g0, be0, h, N);
    // --- Layer 1 ---
    gemm_yz<<<dim3(gridM, 4), 256, 0, stream>>>(h, Wl1, Wr1, b1, yz, N, 128);
    agg_ln128<<<gridNode, 256, 0, stream>>>(offs, ssrc, yz, g1, be1, h, N);
    // --- Layer 2 (outputs 64 feats, no LN/ReLU) ---
    gemm_yz<<<dim3(gridM, 2), 256, 0, stream>>>(h, Wl2, Wr2, b2, yz, N, 64);
    agg_out64<<<gridNode, 256, 0, stream>>>(offs, ssrc, yz, out, N);
}

// Round 4
// 594.668 us; speedup vs baseline: 16.7143x; 1.5129x over previous
//
#include <hip/hip_runtime.h>

// ---------------------------------------------------------------------------
// GraphSAGE 3-layer forward, MI355X.
//   CSR build (count -> 3-pass parallel scan -> fill) reused by all layers.
//   Per layer: bf16 MFMA GEMM  [y|z] = A @ [Wl;Wr].T  (fp32 accum),
//     y half stored bf16 (feeds mean-aggregation; rounding averages down),
//     z half + bias stored fp32 (self path stays exact),
//   then gather-mean over in-edges + z + ReLU + LayerNorm -> h (bf16).
// R3->R4: fp32 vector GEMM (45 TF, MfmaUtil 0) -> mfma_f32_16x16x32_bf16.
// ---------------------------------------------------------------------------

typedef __bf16 bf16x8 __attribute__((ext_vector_type(8)));
typedef __bf16 bf16x4 __attribute__((ext_vector_type(4)));
typedef float  f32x4  __attribute__((ext_vector_type(4)));

__global__ void count_deg(const int* __restrict__ dst, int* __restrict__ deg, int E) {
    int e = blockIdx.x * blockDim.x + threadIdx.x;
    if (e < E) atomicAdd(&deg[dst[e]], 1);
}

#define SB 256
#define SE 4096

__global__ __launch_bounds__(SB) void scan_block_sums(const int* __restrict__ deg,
                                                      int* __restrict__ bsums, int n) {
    __shared__ int red[SB / 64];
    int t = threadIdx.x;
    int base = blockIdx.x * SE + t * 16;
    int s = 0;
#pragma unroll
    for (int i = 0; i < 16; ++i) {
        int idx = base + i;
        if (idx < n) s += deg[idx];
    }
#pragma unroll
    for (int off = 32; off >= 1; off >>= 1) s += __shfl_xor(s, off, 64);
    if ((t & 63) == 0) red[t >> 6] = s;
    __syncthreads();
    if (t == 0) {
        int tot = 0;
#pragma unroll
        for (int w = 0; w < SB / 64; ++w) tot += red[w];
        bsums[blockIdx.x] = tot;
    }
}

__global__ __launch_bounds__(1024) void scan_partials(int* __restrict__ bsums,
                                                      int* __restrict__ offs,
                                                      int nb, int n) {
    __shared__ int sm[1024];
    int t = threadIdx.x;
    int v = (t < nb) ? bsums[t] : 0;
    sm[t] = v;
    __syncthreads();
    for (int off = 1; off < 1024; off <<= 1) {
        int add = (t >= off) ? sm[t - off] : 0;
        __syncthreads();
        sm[t] += add;
        __syncthreads();
    }
    if (t < nb) bsums[t] = sm[t] - v;
    if (t == 1023) offs[n] = sm[1023];
}

__global__ __launch_bounds__(SB) void scan_final(int* __restrict__ degc,
                                                 const int* __restrict__ bsums,
                                                 int* __restrict__ offs, int n) {
    __shared__ int tsum[SB];
    int t = threadIdx.x;
    int base = blockIdx.x * SE + t * 16;
    int vals[16];
    int s = 0;
#pragma unroll
    for (int i = 0; i < 16; ++i) {
        int idx = base + i;
        vals[i] = (idx < n) ? degc[idx] : 0;
        s += vals[i];
    }
    tsum[t] = s;
    __syncthreads();
    for (int off = 1; off < SB; off <<= 1) {
        int add = (t >= off) ? tsum[t - off] : 0;
        __syncthreads();
        tsum[t] += add;
        __syncthreads();
    }
    int run = bsums[blockIdx.x] + tsum[t] - s;
#pragma unroll
    for (int i = 0; i < 16; ++i) {
        int idx = base + i;
        if (idx < n) {
            offs[idx] = run;
            degc[idx] = run;
            run += vals[i];
        }
    }
}

__global__ void fill_csr(const int* __restrict__ src, const int* __restrict__ dst,
                         int* __restrict__ cursor, int* __restrict__ sorted_src, int E) {
    int e = blockIdx.x * blockDim.x + threadIdx.x;
    if (e < E) {
        int p = atomicAdd(&cursor[dst[e]], 1);
        sorted_src[p] = src[e];
    }
}

// fp32 -> bf16 cast, 4 elems/thread (n multiple of 4 here).
__global__ void f2bf(const float* __restrict__ in, __bf16* __restrict__ out, int n) {
    int i = (blockIdx.x * blockDim.x + threadIdx.x) * 4;
    if (i + 3 < n) {
        float4 v = *(const float4*)(in + i);
        bf16x4 o;
        o[0] = (__bf16)v.x; o[1] = (__bf16)v.y; o[2] = (__bf16)v.z; o[3] = (__bf16)v.w;
        *(bf16x4*)(out + i) = o;
    }
}

// ---------------------------------------------------------------------------
// MFMA GEMM: A[M][128] bf16 @ [Wl;Wr][dout][128].T
//   y half (cols < dout)  -> ybuf bf16 [M][dout]
//   z half (cols >= dout) -> zbuf fp32 [M][dout], + bias
// Block: 64 rows x 64 cols, 4 waves (2x2), each wave 2x2 of 16x16 tiles,
// K=128 in LDS (row stride 136 bf16 -> 2-way bank aliasing = free).
// W staged fp32->bf16 on the fly (no separate weight convert kernels).
// ---------------------------------------------------------------------------
__global__ __launch_bounds__(256) void gemm_mfma(
    const __bf16* __restrict__ A,
    const float* __restrict__ Wl,
    const float* __restrict__ Wr,
    const float* __restrict__ bias,
    __bf16* __restrict__ ybuf,
    float*  __restrict__ zbuf,
    int M, int dout) {
    __shared__ __bf16 Asm[64 * 136];
    __shared__ __bf16 Bsm[64 * 136];

    const int t = threadIdx.x;
    const int rowBase = blockIdx.x * 64;
    const int by = blockIdx.y;
    const int nyHalf = dout >> 6;
    const bool isZ = by >= nyHalf;
    const float* W = isZ ? Wr : Wl;
    const int colLocal = (by - (isZ ? nyHalf : 0)) * 64;

    // A tile: 64x128 bf16 = 1024 x 16B chunks, 4 per thread.
#pragma unroll
    for (int i = 0; i < 4; ++i) {
        int idx = t + 256 * i;
        int r = idx >> 4;
        int c8 = idx & 15;
        int grow = rowBase + r;
        if (grow >= M) grow = M - 1;
        bf16x8 v = *(const bf16x8*)(A + (size_t)grow * 128 + c8 * 8);
        *(bf16x8*)(Asm + r * 136 + c8 * 8) = v;
    }
    // W tile: 64x128 fp32, convert to bf16 while staging.
#pragma unroll
    for (int i = 0; i < 8; ++i) {
        int idx = t + 256 * i;
        int r = idx >> 5;
        int c4 = idx & 31;
        float4 v = *(const float4*)(W + (size_t)(colLocal + r) * 128 + c4 * 4);
        bf16x4 o;
        o[0] = (__bf16)v.x; o[1] = (__bf16)v.y; o[2] = (__bf16)v.z; o[3] = (__bf16)v.w;
        *(bf16x4*)(Bsm + r * 136 + c4 * 4) = o;
    }
    __syncthreads();

    const int lane = t & 63;
    const int wid = t >> 6;
    const int mb = (wid >> 1) * 32;
    const int nb = (wid & 1) * 32;
    const int ln = lane & 15;
    const int qk = lane >> 4;

    f32x4 acc[2][2] = {};
#pragma unroll
    for (int ks = 0; ks < 4; ++ks) {
        const int k0 = ks * 32 + qk * 8;
        bf16x8 a0 = *(const bf16x8*)(Asm + (mb + ln) * 136 + k0);
        bf16x8 a1 = *(const bf16x8*)(Asm + (mb + 16 + ln) * 136 + k0);
        bf16x8 b0 = *(const bf16x8*)(Bsm + (nb + ln) * 136 + k0);
        bf16x8 b1 = *(const bf16x8*)(Bsm + (nb + 16 + ln) * 136 + k0);
        acc[0][0] = __builtin_amdgcn_mfma_f32_16x16x32_bf16(a0, b0, acc[0][0], 0, 0, 0);
        acc[0][1] = __builtin_amdgcn_mfma_f32_16x16x32_bf16(a0, b1, acc[0][1], 0, 0, 0);
        acc[1][0] = __builtin_amdgcn_mfma_f32_16x16x32_bf16(a1, b0, acc[1][0], 0, 0, 0);
        acc[1][1] = __builtin_amdgcn_mfma_f32_16x16x32_bf16(a1, b1, acc[1][1], 0, 0, 0);
    }

    // C/D: col = lane&15, row = (lane>>4)*4 + reg  [m89-verified]
#pragma unroll
    for (int i = 0; i < 2; ++i) {
#pragma unroll
        for (int r = 0; r < 4; ++r) {
            int grow = rowBase + mb + i * 16 + qk * 4 + r;
            if (grow >= M) continue;
#pragma unroll
            for (int j = 0; j < 2; ++j) {
                int col = colLocal + nb + j * 16 + ln;
                float v = acc[i][j][r];
                if (isZ) zbuf[(size_t)grow * dout + col] = v + bias[col];
                else     ybuf[(size_t)grow * dout + col] = (__bf16)v;
            }
        }
    }
}

// ---------------------------------------------------------------------------
// Aggregation 128f: wave/node; 4 edges per iter (lane quads read 16B bf16x8).
// mean(y bf16) + z(fp32) -> ReLU -> LN -> h (bf16).
// ---------------------------------------------------------------------------
__global__ __launch_bounds__(256) void agg_ln128(
    const int* __restrict__ offs, const int* __restrict__ ssrc,
    const __bf16* __restrict__ ybuf,   // [N][128]
    const float* __restrict__ zbuf,    // [N][128]
    const float* __restrict__ gamma, const float* __restrict__ beta,
    __bf16* __restrict__ hout, int nNodes) {
    const int lane = threadIdx.x & 63;
    const int qh = lane >> 4;
    const int li = lane & 15;
    const int node = blockIdx.x * 4 + (threadIdx.x >> 6);
    if (node >= nNodes) return;
    const int beg = offs[node], end = offs[node + 1];

    float acc[8] = {};
    for (int j = beg; j < end; j += 64) {
        int cnt = end - j;
        if (cnt > 64) cnt = 64;
        int sidx = ssrc[j + ((lane < cnt) ? lane : 0)];
        int quads = (cnt + 3) >> 2;
        for (int u = 0; u < quads; ++u) {
            int e = 4 * u + qh;
            int s = __shfl(sidx, (e < cnt) ? e : 0, 64);
            if (e < cnt) {
                bf16x8 v = *(const bf16x8*)(ybuf + (size_t)s * 128 + li * 8);
#pragma unroll
                for (int m = 0; m < 8; ++m) acc[m] += (float)v[m];
            }
        }
    }
#pragma unroll
    for (int m = 0; m < 8; ++m) {
        acc[m] += __shfl_xor(acc[m], 16, 64);
        acc[m] += __shfl_xor(acc[m], 32, 64);
    }
    int degn = end - beg;
    float inv = 1.f / (float)((degn > 1) ? degn : 1);
    const float4* z4 = (const float4*)(zbuf + (size_t)node * 128 + li * 8);
    float4 z0 = z4[0], z1 = z4[1];
    float v[8];
    v[0] = fmaxf(acc[0] * inv + z0.x, 0.f);
    v[1] = fmaxf(acc[1] * inv + z0.y, 0.f);
    v[2] = fmaxf(acc[2] * inv + z0.z, 0.f);
    v[3] = fmaxf(acc[3] * inv + z0.w, 0.f);
    v[4] = fmaxf(acc[4] * inv + z1.x, 0.f);
    v[5] = fmaxf(acc[5] * inv + z1.y, 0.f);
    v[6] = fmaxf(acc[6] * inv + z1.z, 0.f);
    v[7] = fmaxf(acc[7] * inv + z1.w, 0.f);

    float s = 0.f;
#pragma unroll
    for (int m = 0; m < 8; ++m) s += v[m];
#pragma unroll
    for (int off = 8; off >= 1; off >>= 1) s += __shfl_xor(s, off, 64);
    float mu = s * (1.f / 128.f);
    float d[8], q = 0.f;
#pragma unroll
    for (int m = 0; m < 8; ++m) { d[m] = v[m] - mu; q += d[m] * d[m]; }
#pragma unroll
    for (int off = 8; off >= 1; off >>= 1) q += __shfl_xor(q, off, 64);
    float rstd = rsqrtf(q * (1.f / 128.f) + 1e-5f);

    if (qh == 0) {
        const float4* g4 = (const float4*)(gamma + li * 8);
        const float4* b4 = (const float4*)(beta + li * 8);
        float4 g0 = g4[0], g1 = g4[1], bb0 = b4[0], bb1 = b4[1];
        bf16x8 o;
        o[0] = (__bf16)(d[0] * rstd * g0.x + bb0.x);
        o[1] = (__bf16)(d[1] * rstd * g0.y + bb0.y);
        o[2] = (__bf16)(d[2] * rstd * g0.z + bb0.z);
        o[3] = (__bf16)(d[3] * rstd * g0.w + bb0.w);
        o[4] = (__bf16)(d[4] * rstd * g1.x + bb1.x);
        o[5] = (__bf16)(d[5] * rstd * g1.y + bb1.y);
        o[6] = (__bf16)(d[6] * rstd * g1.z + bb1.z);
        o[7] = (__bf16)(d[7] * rstd * g1.w + bb1.w);
        *(bf16x8*)(hout + (size_t)node * 128 + li * 8) = o;
    }
}

// Aggregation 64f (final): 8 edges per iter; mean(y bf16) + z(fp32) -> out fp32.
__global__ __launch_bounds__(256) void agg_out64(
    const int* __restrict__ offs, const int* __restrict__ ssrc,
    const __bf16* __restrict__ ybuf,   // [N][64]
    const float* __restrict__ zbuf,    // [N][64]
    float* __restrict__ out, int nNodes) {
    const int lane = threadIdx.x & 63;
    const int eh = lane >> 3;
    const int li = lane & 7;
    const int node = blockIdx.x * 4 + (threadIdx.x >> 6);
    if (node >= nNodes) return;
    const int beg = offs[node], end = offs[node + 1];

    float acc[8] = {};
    for (int j = beg; j < end; j += 64) {
        int cnt = end - j;
        if (cnt > 64) cnt = 64;
        int sidx = ssrc[j + ((lane < cnt) ? lane : 0)];
        int octs = (cnt + 7) >> 3;
        for (int u = 0; u < octs; ++u) {
            int e = 8 * u + eh;
            int s = __shfl(sidx, (e < cnt) ? e : 0, 64);
            if (e < cnt) {
                bf16x8 v = *(const bf16x8*)(ybuf + (size_t)s * 64 + li * 8);
#pragma unroll
                for (int m = 0; m < 8; ++m) acc[m] += (float)v[m];
            }
        }
    }
#pragma unroll
    for (int m = 0; m < 8; ++m) {
        acc[m] += __shfl_xor(acc[m], 8, 64);
        acc[m] += __shfl_xor(acc[m], 16, 64);
        acc[m] += __shfl_xor(acc[m], 32, 64);
    }
    if (eh == 0) {
        int degn = end - beg;
        float inv = 1.f / (float)((degn > 1) ? degn : 1);
        const float4* z4 = (const float4*)(zbuf + (size_t)node * 64 + li * 8);
        float4 z0 = z4[0], z1 = z4[1];
        float4 o0, o1;
        o0.x = acc[0] * inv + z0.x;
        o0.y = acc[1] * inv + z0.y;
        o0.z = acc[2] * inv + z0.z;
        o0.w = acc[3] * inv + z0.w;
        o1.x = acc[4] * inv + z1.x;
        o1.y = acc[5] * inv + z1.y;
        o1.z = acc[6] * inv + z1.z;
        o1.w = acc[7] * inv + z1.w;
        float4* op = (float4*)(out + (size_t)node * 64 + li * 8);
        op[0] = o0;
        op[1] = o1;
    }
}

// ---------------------------------------------------------------------------
extern "C" void kernel_launch(void* const* d_in, const int* in_sizes, int n_in,
                              void* d_out, int out_size, void* d_ws, size_t ws_size,
                              hipStream_t stream) {
    const float* x   = (const float*)d_in[0];
    const int*   ei  = (const int*)d_in[1];
    const float* Wl0 = (const float*)d_in[2];
    const float* Wr0 = (const float*)d_in[3];
    const float* b0  = (const float*)d_in[4];
    const float* Wl1 = (const float*)d_in[5];
    const float* Wr1 = (const float*)d_in[6];
    const float* b1  = (const float*)d_in[7];
    const float* Wl2 = (const float*)d_in[8];
    const float* Wr2 = (const float*)d_in[9];
    const float* b2  = (const float*)d_in[10];
    const float* g0  = (const float*)d_in[11];
    const float* be0 = (const float*)d_in[12];
    const float* g1  = (const float*)d_in[13];
    const float* be1 = (const float*)d_in[14];

    const int N = in_sizes[0] / 128;
    const int E = in_sizes[1] / 2;
    const int* src = ei;
    const int* dst = ei + E;
    float* out = (float*)d_out;

    char* p = (char*)d_ws;
    auto carve = [&](size_t bytes) {
        void* q = (void*)p;
        p += (bytes + 255) & ~(size_t)255;
        return q;
    };
    const int nb = (N + SE - 1) / SE;
    int*     offs  = (int*)carve(sizeof(int) * (size_t)(N + 1));
    int*     degc  = (int*)carve(sizeof(int) * (size_t)N);
    int*     bsums = (int*)carve(sizeof(int) * (size_t)nb);
    int*     ssrc  = (int*)carve(sizeof(int) * (size_t)E);
    __bf16*  xb    = (__bf16*)carve(sizeof(__bf16) * (size_t)N * 128);
    __bf16*  h     = (__bf16*)carve(sizeof(__bf16) * (size_t)N * 128);
    __bf16*  ybuf  = (__bf16*)carve(sizeof(__bf16) * (size_t)N * 128);
    float*   zbuf  = (float*)carve(sizeof(float) * (size_t)N * 128);

    // --- CSR build ---
    hipMemsetAsync(degc, 0, sizeof(int) * (size_t)N, stream);
    count_deg<<<(E + 255) / 256, 256, 0, stream>>>(dst, degc, E);
    scan_block_sums<<<nb, SB, 0, stream>>>(degc, bsums, N);
    scan_partials<<<1, 1024, 0, stream>>>(bsums, offs, nb, N);
    scan_final<<<nb, SB, 0, stream>>>(degc, bsums, offs, N);
    fill_csr<<<(E + 255) / 256, 256, 0, stream>>>(src, dst, degc, ssrc, E);

    // --- x -> bf16 ---
    f2bf<<<(N * 128 / 4 + 255) / 256, 256, 0, stream>>>(x, xb, N * 128);

    const int gridM = (N + 63) / 64;
    const int gridNode = (N + 3) / 4;

    // --- Layer 0 ---
    gemm_mfma<<<dim3(gridM, 4), 256, 0, stream>>>(xb, Wl0, Wr0, b0, ybuf, zbuf, N, 128);
    agg_ln128<<<gridNode, 256, 0, stream>>>(offs, ssrc, ybuf, zbuf, g0, be0, h, N);
    // --- Layer 1 ---
    gemm_mfma<<<dim3(gridM, 4), 256, 0, stream>>>(h, Wl1, Wr1, b1, ybuf, zbuf, N, 128);
    agg_ln128<<<gridNode, 256, 0, stream>>>(offs, ssrc, ybuf, zbuf, g1, be1, h, N);
    // --- Layer 2 ---
    gemm_mfma<<<dim3(gridM, 2), 256, 0, stream>>>(h, Wl2, Wr2, b2, ybuf, zbuf, N, 64);
    agg_out64<<<gridNode, 256, 0, stream>>>(offs, ssrc, ybuf, zbuf, out, N);
}

// Round 5
// 561.111 us; speedup vs baseline: 17.7139x; 1.0598x over previous
//
#include <hip/hip_runtime.h>

// ---------------------------------------------------------------------------
// GraphSAGE 3-layer forward, MI355X.
//   CSR build: count -> 3-pass parallel scan -> two-level counting sort
//     (coarse 512-node bucket partition, then in-bucket fine fill).
//   Per layer: bf16 MFMA GEMM  [y|z] = A @ [Wl;Wr].T  (fp32 accum),
//     y bf16 (feeds mean-agg), z+bias fp32 (self path exact),
//   then gather-mean + z + ReLU + LayerNorm -> h (bf16).
// R4->R5: fill_csr was HBM-write-amplification-bound (105 MB writes for a
// 6.4 MB array, 125 us). Two-level sort makes writes dense: coarse runs are
// contiguous; fine scatter confined to 32 KB L2-resident windows.
// ---------------------------------------------------------------------------

typedef __bf16 bf16x8 __attribute__((ext_vector_type(8)));
typedef __bf16 bf16x4 __attribute__((ext_vector_type(4)));
typedef float  f32x4  __attribute__((ext_vector_type(4)));

__global__ void count_deg(const int* __restrict__ dst, int* __restrict__ deg, int E) {
    int e = blockIdx.x * blockDim.x + threadIdx.x;
    if (e < E) atomicAdd(&deg[dst[e]], 1);
}

#define SB 256
#define SE 4096

__global__ __launch_bounds__(SB) void scan_block_sums(const int* __restrict__ deg,
                                                      int* __restrict__ bsums, int n) {
    __shared__ int red[SB / 64];
    int t = threadIdx.x;
    int base = blockIdx.x * SE + t * 16;
    int s = 0;
#pragma unroll
    for (int i = 0; i < 16; ++i) {
        int idx = base + i;
        if (idx < n) s += deg[idx];
    }
#pragma unroll
    for (int off = 32; off >= 1; off >>= 1) s += __shfl_xor(s, off, 64);
    if ((t & 63) == 0) red[t >> 6] = s;
    __syncthreads();
    if (t == 0) {
        int tot = 0;
#pragma unroll
        for (int w = 0; w < SB / 64; ++w) tot += red[w];
        bsums[blockIdx.x] = tot;
    }
}

__global__ __launch_bounds__(1024) void scan_partials(int* __restrict__ bsums,
                                                      int* __restrict__ offs,
                                                      int nb, int n) {
    __shared__ int sm[1024];
    int t = threadIdx.x;
    int v = (t < nb) ? bsums[t] : 0;
    sm[t] = v;
    __syncthreads();
    for (int off = 1; off < 1024; off <<= 1) {
        int add = (t >= off) ? sm[t - off] : 0;
        __syncthreads();
        sm[t] += add;
        __syncthreads();
    }
    if (t < nb) bsums[t] = sm[t] - v;
    if (t == 1023) offs[n] = sm[1023];
}

__global__ __launch_bounds__(SB) void scan_final(int* __restrict__ degc,
                                                 const int* __restrict__ bsums,
                                                 int* __restrict__ offs, int n) {
    __shared__ int tsum[SB];
    int t = threadIdx.x;
    int base = blockIdx.x * SE + t * 16;
    int vals[16];
    int s = 0;
#pragma unroll
    for (int i = 0; i < 16; ++i) {
        int idx = base + i;
        vals[i] = (idx < n) ? degc[idx] : 0;
        s += vals[i];
    }
    tsum[t] = s;
    __syncthreads();
    for (int off = 1; off < SB; off <<= 1) {
        int add = (t >= off) ? tsum[t - off] : 0;
        __syncthreads();
        tsum[t] += add;
        __syncthreads();
    }
    int run = bsums[blockIdx.x] + tsum[t] - s;
#pragma unroll
    for (int i = 0; i < 16; ++i) {
        int idx = base + i;
        if (idx < n) {
            offs[idx] = run;
            degc[idx] = run;
            run += vals[i];
        }
    }
}

// ---------------- two-level counting sort (replaces fill_csr) ----------------
#define PB_SHIFT 9                      // 512 nodes per coarse bucket
#define PB_NB    256                    // covers N <= 131072
#define PB_EPT   8
#define PB_BLOCK 256
#define PB_CHUNK (PB_BLOCK * PB_EPT)    // 2048 edges per block

// bcursor[b] = offs[min(b*512, n)] — coarse bucket base, free from node scan.
__global__ void init_bcursor(const int* __restrict__ offs, int* __restrict__ bcursor,
                             int n) {
    int b = threadIdx.x;  // one block of 256
    int node = b << PB_SHIFT;
    bcursor[b] = offs[node < n ? node : n];
}

// Coarse partition: per-block LDS histogram -> one global reservation per
// (block,bucket) -> contiguous ~84 B runs of int2 (dense writes).
__global__ __launch_bounds__(PB_BLOCK) void part_scatter(
    const int* __restrict__ src, const int* __restrict__ dst,
    int* __restrict__ bcursor, int2* __restrict__ part, int E) {
    __shared__ int hist[PB_NB];
    __shared__ int base[PB_NB];
    const int t = threadIdx.x;
    for (int i = t; i < PB_NB; i += PB_BLOCK) hist[i] = 0;
    __syncthreads();
    const int e0 = blockIdx.x * PB_CHUNK + t;
    int my_s[PB_EPT], my_d[PB_EPT], my_r[PB_EPT];
#pragma unroll
    for (int i = 0; i < PB_EPT; ++i) {
        int e = e0 + i * PB_BLOCK;
        if (e < E) {
            my_s[i] = src[e];
            my_d[i] = dst[e];
            my_r[i] = atomicAdd(&hist[my_d[i] >> PB_SHIFT], 1);
        }
    }
    __syncthreads();
    for (int b = t; b < PB_NB; b += PB_BLOCK) {
        int c = hist[b];
        base[b] = c ? atomicAdd(&bcursor[b], c) : 0;
    }
    __syncthreads();
#pragma unroll
    for (int i = 0; i < PB_EPT; ++i) {
        int e = e0 + i * PB_BLOCK;
        if (e < E) {
            int b = my_d[i] >> PB_SHIFT;
            part[base[b] + my_r[i]] = make_int2(my_s[i], my_d[i]);
        }
    }
}

// Fine fill: edges now bucket-grouped; each block's scatter stays inside a
// ~32 KB node window -> lines fill in L2 before eviction.
__global__ __launch_bounds__(PB_BLOCK) void fine_fill(
    const int2* __restrict__ part, int* __restrict__ cursor,
    int* __restrict__ ssrc, int E) {
    const int e0 = blockIdx.x * PB_CHUNK + threadIdx.x;
#pragma unroll
    for (int i = 0; i < PB_EPT; ++i) {
        int e = e0 + i * PB_BLOCK;
        if (e < E) {
            int2 sd = part[e];
            int p = atomicAdd(&cursor[sd.y], 1);
            ssrc[p] = sd.x;
        }
    }
}

// fp32 -> bf16 cast, 4 elems/thread.
__global__ void f2bf(const float* __restrict__ in, __bf16* __restrict__ out, int n) {
    int i = (blockIdx.x * blockDim.x + threadIdx.x) * 4;
    if (i + 3 < n) {
        float4 v = *(const float4*)(in + i);
        bf16x4 o;
        o[0] = (__bf16)v.x; o[1] = (__bf16)v.y; o[2] = (__bf16)v.z; o[3] = (__bf16)v.w;
        *(bf16x4*)(out + i) = o;
    }
}

// ---------------------------------------------------------------------------
// MFMA GEMM: A[M][128] bf16 @ [Wl;Wr][dout][128].T
//   y half -> ybuf bf16 [M][dout];  z half -> zbuf fp32 [M][dout] + bias.
// 64x64 block tile, 4 waves 2x2, K=128 LDS-resident (stride 136 bf16).
// ---------------------------------------------------------------------------
__global__ __launch_bounds__(256) void gemm_mfma(
    const __bf16* __restrict__ A,
    const float* __restrict__ Wl,
    const float* __restrict__ Wr,
    const float* __restrict__ bias,
    __bf16* __restrict__ ybuf,
    float*  __restrict__ zbuf,
    int M, int dout) {
    __shared__ __bf16 Asm[64 * 136];
    __shared__ __bf16 Bsm[64 * 136];

    const int t = threadIdx.x;
    const int rowBase = blockIdx.x * 64;
    const int by = blockIdx.y;
    const int nyHalf = dout >> 6;
    const bool isZ = by >= nyHalf;
    const float* W = isZ ? Wr : Wl;
    const int colLocal = (by - (isZ ? nyHalf : 0)) * 64;

#pragma unroll
    for (int i = 0; i < 4; ++i) {
        int idx = t + 256 * i;
        int r = idx >> 4;
        int c8 = idx & 15;
        int grow = rowBase + r;
        if (grow >= M) grow = M - 1;
        bf16x8 v = *(const bf16x8*)(A + (size_t)grow * 128 + c8 * 8);
        *(bf16x8*)(Asm + r * 136 + c8 * 8) = v;
    }
#pragma unroll
    for (int i = 0; i < 8; ++i) {
        int idx = t + 256 * i;
        int r = idx >> 5;
        int c4 = idx & 31;
        float4 v = *(const float4*)(W + (size_t)(colLocal + r) * 128 + c4 * 4);
        bf16x4 o;
        o[0] = (__bf16)v.x; o[1] = (__bf16)v.y; o[2] = (__bf16)v.z; o[3] = (__bf16)v.w;
        *(bf16x4*)(Bsm + r * 136 + c4 * 4) = o;
    }
    __syncthreads();

    const int lane = t & 63;
    const int wid = t >> 6;
    const int mb = (wid >> 1) * 32;
    const int nb = (wid & 1) * 32;
    const int ln = lane & 15;
    const int qk = lane >> 4;

    f32x4 acc[2][2] = {};
#pragma unroll
    for (int ks = 0; ks < 4; ++ks) {
        const int k0 = ks * 32 + qk * 8;
        bf16x8 a0 = *(const bf16x8*)(Asm + (mb + ln) * 136 + k0);
        bf16x8 a1 = *(const bf16x8*)(Asm + (mb + 16 + ln) * 136 + k0);
        bf16x8 b0 = *(const bf16x8*)(Bsm + (nb + ln) * 136 + k0);
        bf16x8 b1 = *(const bf16x8*)(Bsm + (nb + 16 + ln) * 136 + k0);
        acc[0][0] = __builtin_amdgcn_mfma_f32_16x16x32_bf16(a0, b0, acc[0][0], 0, 0, 0);
        acc[0][1] = __builtin_amdgcn_mfma_f32_16x16x32_bf16(a0, b1, acc[0][1], 0, 0, 0);
        acc[1][0] = __builtin_amdgcn_mfma_f32_16x16x32_bf16(a1, b0, acc[1][0], 0, 0, 0);
        acc[1][1] = __builtin_amdgcn_mfma_f32_16x16x32_bf16(a1, b1, acc[1][1], 0, 0, 0);
    }

    // C/D: col = lane&15, row = (lane>>4)*4 + reg  [m89-verified]
#pragma unroll
    for (int i = 0; i < 2; ++i) {
#pragma unroll
        for (int r = 0; r < 4; ++r) {
            int grow = rowBase + mb + i * 16 + qk * 4 + r;
            if (grow >= M) continue;
#pragma unroll
            for (int j = 0; j < 2; ++j) {
                int col = colLocal + nb + j * 16 + ln;
                float v = acc[i][j][r];
                if (isZ) zbuf[(size_t)grow * dout + col] = v + bias[col];
                else     ybuf[(size_t)grow * dout + col] = (__bf16)v;
            }
        }
    }
}

// ---------------------------------------------------------------------------
// Aggregation 128f: wave/node; 4 edges per iter (lane quads read 16B bf16x8).
// mean(y bf16) + z(fp32) -> ReLU -> LN -> h (bf16).
// ---------------------------------------------------------------------------
__global__ __launch_bounds__(256) void agg_ln128(
    const int* __restrict__ offs, const int* __restrict__ ssrc,
    const __bf16* __restrict__ ybuf,   // [N][128]
    const float* __restrict__ zbuf,    // [N][128]
    const float* __restrict__ gamma, const float* __restrict__ beta,
    __bf16* __restrict__ hout, int nNodes) {
    const int lane = threadIdx.x & 63;
    const int qh = lane >> 4;
    const int li = lane & 15;
    const int node = blockIdx.x * 4 + (threadIdx.x >> 6);
    if (node >= nNodes) return;
    const int beg = offs[node], end = offs[node + 1];

    float acc[8] = {};
    for (int j = beg; j < end; j += 64) {
        int cnt = end - j;
        if (cnt > 64) cnt = 64;
        int sidx = ssrc[j + ((lane < cnt) ? lane : 0)];
        int quads = (cnt + 3) >> 2;
        for (int u = 0; u < quads; ++u) {
            int e = 4 * u + qh;
            int s = __shfl(sidx, (e < cnt) ? e : 0, 64);
            if (e < cnt) {
                bf16x8 v = *(const bf16x8*)(ybuf + (size_t)s * 128 + li * 8);
#pragma unroll
                for (int m = 0; m < 8; ++m) acc[m] += (float)v[m];
            }
        }
    }
#pragma unroll
    for (int m = 0; m < 8; ++m) {
        acc[m] += __shfl_xor(acc[m], 16, 64);
        acc[m] += __shfl_xor(acc[m], 32, 64);
    }
    int degn = end - beg;
    float inv = 1.f / (float)((degn > 1) ? degn : 1);
    const float4* z4 = (const float4*)(zbuf + (size_t)node * 128 + li * 8);
    float4 z0 = z4[0], z1 = z4[1];
    float v[8];
    v[0] = fmaxf(acc[0] * inv + z0.x, 0.f);
    v[1] = fmaxf(acc[1] * inv + z0.y, 0.f);
    v[2] = fmaxf(acc[2] * inv + z0.z, 0.f);
    v[3] = fmaxf(acc[3] * inv + z0.w, 0.f);
    v[4] = fmaxf(acc[4] * inv + z1.x, 0.f);
    v[5] = fmaxf(acc[5] * inv + z1.y, 0.f);
    v[6] = fmaxf(acc[6] * inv + z1.z, 0.f);
    v[7] = fmaxf(acc[7] * inv + z1.w, 0.f);

    float s = 0.f;
#pragma unroll
    for (int m = 0; m < 8; ++m) s += v[m];
#pragma unroll
    for (int off = 8; off >= 1; off >>= 1) s += __shfl_xor(s, off, 64);
    float mu = s * (1.f / 128.f);
    float d[8], q = 0.f;
#pragma unroll
    for (int m = 0; m < 8; ++m) { d[m] = v[m] - mu; q += d[m] * d[m]; }
#pragma unroll
    for (int off = 8; off >= 1; off >>= 1) q += __shfl_xor(q, off, 64);
    float rstd = rsqrtf(q * (1.f / 128.f) + 1e-5f);

    if (qh == 0) {
        const float4* g4 = (const float4*)(gamma + li * 8);
        const float4* b4 = (const float4*)(beta + li * 8);
        float4 g0 = g4[0], g1 = g4[1], bb0 = b4[0], bb1 = b4[1];
        bf16x8 o;
        o[0] = (__bf16)(d[0] * rstd * g0.x + bb0.x);
        o[1] = (__bf16)(d[1] * rstd * g0.y + bb0.y);
        o[2] = (__bf16)(d[2] * rstd * g0.z + bb0.z);
        o[3] = (__bf16)(d[3] * rstd * g0.w + bb0.w);
        o[4] = (__bf16)(d[4] * rstd * g1.x + bb1.x);
        o[5] = (__bf16)(d[5] * rstd * g1.y + bb1.y);
        o[6] = (__bf16)(d[6] * rstd * g1.z + bb1.z);
        o[7] = (__bf16)(d[7] * rstd * g1.w + bb1.w);
        *(bf16x8*)(hout + (size_t)node * 128 + li * 8) = o;
    }
}

// Aggregation 64f (final): 8 edges per iter; mean(y bf16) + z(fp32) -> out fp32.
__global__ __launch_bounds__(256) void agg_out64(
    const int* __restrict__ offs, const int* __restrict__ ssrc,
    const __bf16* __restrict__ ybuf,   // [N][64]
    const float* __restrict__ zbuf,    // [N][64]
    float* __restrict__ out, int nNodes) {
    const int lane = threadIdx.x & 63;
    const int eh = lane >> 3;
    const int li = lane & 7;
    const int node = blockIdx.x * 4 + (threadIdx.x >> 6);
    if (node >= nNodes) return;
    const int beg = offs[node], end = offs[node + 1];

    float acc[8] = {};
    for (int j = beg; j < end; j += 64) {
        int cnt = end - j;
        if (cnt > 64) cnt = 64;
        int sidx = ssrc[j + ((lane < cnt) ? lane : 0)];
        int octs = (cnt + 7) >> 3;
        for (int u = 0; u < octs; ++u) {
            int e = 8 * u + eh;
            int s = __shfl(sidx, (e < cnt) ? e : 0, 64);
            if (e < cnt) {
                bf16x8 v = *(const bf16x8*)(ybuf + (size_t)s * 64 + li * 8);
#pragma unroll
                for (int m = 0; m < 8; ++m) acc[m] += (float)v[m];
            }
        }
    }
#pragma unroll
    for (int m = 0; m < 8; ++m) {
        acc[m] += __shfl_xor(acc[m], 8, 64);
        acc[m] += __shfl_xor(acc[m], 16, 64);
        acc[m] += __shfl_xor(acc[m], 32, 64);
    }
    if (eh == 0) {
        int degn = end - beg;
        float inv = 1.f / (float)((degn > 1) ? degn : 1);
        const float4* z4 = (const float4*)(zbuf + (size_t)node * 64 + li * 8);
        float4 z0 = z4[0], z1 = z4[1];
        float4 o0, o1;
        o0.x = acc[0] * inv + z0.x;
        o0.y = acc[1] * inv + z0.y;
        o0.z = acc[2] * inv + z0.z;
        o0.w = acc[3] * inv + z0.w;
        o1.x = acc[4] * inv + z1.x;
        o1.y = acc[5] * inv + z1.y;
        o1.z = acc[6] * inv + z1.z;
        o1.w = acc[7] * inv + z1.w;
        float4* op = (float4*)(out + (size_t)node * 64 + li * 8);
        op[0] = o0;
        op[1] = o1;
    }
}

// ---------------------------------------------------------------------------
extern "C" void kernel_launch(void* const* d_in, const int* in_sizes, int n_in,
                              void* d_out, int out_size, void* d_ws, size_t ws_size,
                              hipStream_t stream) {
    const float* x   = (const float*)d_in[0];
    const int*   ei  = (const int*)d_in[1];
    const float* Wl0 = (const float*)d_in[2];
    const float* Wr0 = (const float*)d_in[3];
    const float* b0  = (const float*)d_in[4];
    const float* Wl1 = (const float*)d_in[5];
    const float* Wr1 = (const float*)d_in[6];
    const float* b1  = (const float*)d_in[7];
    const float* Wl2 = (const float*)d_in[8];
    const float* Wr2 = (const float*)d_in[9];
    const float* b2  = (const float*)d_in[10];
    const float* g0  = (const float*)d_in[11];
    const float* be0 = (const float*)d_in[12];
    const float* g1  = (const float*)d_in[13];
    const float* be1 = (const float*)d_in[14];

    const int N = in_sizes[0] / 128;
    const int E = in_sizes[1] / 2;
    const int* src = ei;
    const int* dst = ei + E;
    float* out = (float*)d_out;

    char* p = (char*)d_ws;
    auto carve = [&](size_t bytes) {
        void* q = (void*)p;
        p += (bytes + 255) & ~(size_t)255;
        return q;
    };
    const int nb = (N + SE - 1) / SE;
    int*     offs  = (int*)carve(sizeof(int) * (size_t)(N + 1));
    int*     degc  = (int*)carve(sizeof(int) * (size_t)N);
    int*     bsums = (int*)carve(sizeof(int) * (size_t)nb);
    int*     bcur  = (int*)carve(sizeof(int) * (size_t)PB_NB);
    int*     ssrc  = (int*)carve(sizeof(int) * (size_t)E);
    int2*    part  = (int2*)carve(sizeof(int2) * (size_t)E);
    __bf16*  xb    = (__bf16*)carve(sizeof(__bf16) * (size_t)N * 128);
    __bf16*  h     = (__bf16*)carve(sizeof(__bf16) * (size_t)N * 128);
    __bf16*  ybuf  = (__bf16*)carve(sizeof(__bf16) * (size_t)N * 128);
    float*   zbuf  = (float*)carve(sizeof(float) * (size_t)N * 128);

    // --- CSR build ---
    hipMemsetAsync(degc, 0, sizeof(int) * (size_t)N, stream);
    count_deg<<<(E + 255) / 256, 256, 0, stream>>>(dst, degc, E);
    scan_block_sums<<<nb, SB, 0, stream>>>(degc, bsums, N);
    scan_partials<<<1, 1024, 0, stream>>>(bsums, offs, nb, N);
    scan_final<<<nb, SB, 0, stream>>>(degc, bsums, offs, N);
    init_bcursor<<<1, PB_NB, 0, stream>>>(offs, bcur, N);
    const int gridE = (E + PB_CHUNK - 1) / PB_CHUNK;
    part_scatter<<<gridE, PB_BLOCK, 0, stream>>>(src, dst, bcur, part, E);
    fine_fill<<<gridE, PB_BLOCK, 0, stream>>>(part, degc, ssrc, E);

    // --- x -> bf16 ---
    f2bf<<<(N * 128 / 4 + 255) / 256, 256, 0, stream>>>(x, xb, N * 128);

    const int gridM = (N + 63) / 64;
    const int gridNode = (N + 3) / 4;

    // --- Layer 0 ---
    gemm_mfma<<<dim3(gridM, 4), 256, 0, stream>>>(xb, Wl0, Wr0, b0, ybuf, zbuf, N, 128);
    agg_ln128<<<gridNode, 256, 0, stream>>>(offs, ssrc, ybuf, zbuf, g0, be0, h, N);
    // --- Layer 1 ---
    gemm_mfma<<<dim3(gridM, 4), 256, 0, stream>>>(h, Wl1, Wr1, b1, ybuf, zbuf, N, 128);
    agg_ln128<<<gridNode, 256, 0, stream>>>(offs, ssrc, ybuf, zbuf, g1, be1, h, N);
    // --- Layer 2 ---
    gemm_mfma<<<dim3(gridM, 2), 256, 0, stream>>>(h, Wl2, Wr2, b2, ybuf, zbuf, N, 64);
    agg_out64<<<gridNode, 256, 0, stream>>>(offs, ssrc, ybuf, zbuf, out, N);
}

// Round 6
// 455.364 us; speedup vs baseline: 21.8276x; 1.2322x over previous
//
#include <hip/hip_runtime.h>

// ---------------------------------------------------------------------------
// GraphSAGE 3-layer forward, MI355X.
//   CSR build: coarse 256-bucket histogram -> tiny scan -> part_scatter
//     (bucket-grouped int2 edges, dense writes) -> bucket_build (per-bucket
//     LDS count/scan/scatter -> offs + ssrc). No node-level global atomics.
//   Per layer: bf16 MFMA GEMM [y|z] = A @ [Wl;Wr].T (fp32 accum),
//     y bf16; z bf16 for LN layers, fp32 for the final layer; A is fp32 for
//     layer 0 (converted during LDS staging - f2bf pass deleted).
//   Aggregation: gather-mean + z + ReLU + LayerNorm -> h (bf16).
// R5->R6: the CSR chain (count_deg + 3-pass scan + fine_fill, ~250us of
// invisible middle) replaced by bucket-local LDS build; f2bf folded; z->bf16.
// ---------------------------------------------------------------------------

typedef __bf16 bf16x8 __attribute__((ext_vector_type(8)));
typedef __bf16 bf16x4 __attribute__((ext_vector_type(4)));
typedef float  f32x4  __attribute__((ext_vector_type(4)));

#define PB_SHIFT 9                      // 512 nodes per coarse bucket
#define PB_NB    256                    // covers N <= 131072
#define PB_EPT   8
#define PB_BLOCK 256
#define PB_CHUNK (PB_BLOCK * PB_EPT)    // 2048 edges per block

// Coarse histogram over dst buckets (LDS-staged, one global flush per block).
__global__ __launch_bounds__(PB_BLOCK) void coarse_hist(
    const int* __restrict__ dst, int* __restrict__ bhist, int E) {
    __shared__ int h[PB_NB];
    const int t = threadIdx.x;
    h[t] = 0;
    __syncthreads();
    const int e0 = blockIdx.x * PB_CHUNK + t;
#pragma unroll
    for (int i = 0; i < PB_EPT; ++i) {
        int e = e0 + i * PB_BLOCK;
        if (e < E) atomicAdd(&h[dst[e] >> PB_SHIFT], 1);
    }
    __syncthreads();
    if (h[t]) atomicAdd(&bhist[t], h[t]);
}

// One block: exclusive-scan the 256 bucket counts -> bbase (kept) + bcur (cursor).
__global__ __launch_bounds__(PB_NB) void coarse_scan(
    const int* __restrict__ bhist, int* __restrict__ bbase, int* __restrict__ bcur) {
    __shared__ int sm[PB_NB];
    const int t = threadIdx.x;
    int v = bhist[t];
    sm[t] = v;
    __syncthreads();
    for (int off = 1; off < PB_NB; off <<= 1) {
        int add = (t >= off) ? sm[t - off] : 0;
        __syncthreads();
        sm[t] += add;
        __syncthreads();
    }
    int excl = sm[t] - v;
    bbase[t] = excl;
    bcur[t] = excl;
}

// Coarse partition: per-block LDS histogram -> one global reservation per
// (block,bucket) -> contiguous runs of int2 (dense writes).
__global__ __launch_bounds__(PB_BLOCK) void part_scatter(
    const int* __restrict__ src, const int* __restrict__ dst,
    int* __restrict__ bcursor, int2* __restrict__ part, int E) {
    __shared__ int hist[PB_NB];
    __shared__ int base[PB_NB];
    const int t = threadIdx.x;
    hist[t] = 0;
    __syncthreads();
    const int e0 = blockIdx.x * PB_CHUNK + t;
    int my_s[PB_EPT], my_d[PB_EPT], my_r[PB_EPT];
#pragma unroll
    for (int i = 0; i < PB_EPT; ++i) {
        int e = e0 + i * PB_BLOCK;
        if (e < E) {
            my_s[i] = src[e];
            my_d[i] = dst[e];
            my_r[i] = atomicAdd(&hist[my_d[i] >> PB_SHIFT], 1);
        }
    }
    __syncthreads();
    {
        int c = hist[t];
        base[t] = c ? atomicAdd(&bcursor[t], c) : 0;
    }
    __syncthreads();
#pragma unroll
    for (int i = 0; i < PB_EPT; ++i) {
        int e = e0 + i * PB_BLOCK;
        if (e < E) {
            int b = my_d[i] >> PB_SHIFT;
            part[base[b] + my_r[i]] = make_int2(my_s[i], my_d[i]);
        }
    }
}

// Per-bucket CSR build: one block per bucket. Count 512 local nodes in LDS,
// LDS inclusive scan (512 entries, 256 threads), write offs, LDS-cursor
// scatter of src into the bucket's dense ssrc window. part read twice (L2-hot).
__global__ __launch_bounds__(256) void bucket_build(
    const int2* __restrict__ part, const int* __restrict__ bbase,
    int* __restrict__ offs, int* __restrict__ ssrc, int N, int E) {
    __shared__ int h[512];
    __shared__ int s[512];
    __shared__ int cur[512];
    const int b = blockIdx.x;
    const int t = threadIdx.x;
    const int beg = bbase[b];
    const int end = (b == PB_NB - 1) ? E : bbase[b + 1];

    h[t] = 0; h[t + 256] = 0;
    __syncthreads();
    for (int e = beg + t; e < end; e += 256)
        atomicAdd(&h[part[e].y & 511], 1);
    __syncthreads();
    s[t] = h[t]; s[t + 256] = h[t + 256];
    __syncthreads();
    for (int off = 1; off < 512; off <<= 1) {
        int a0 = (t >= off) ? s[t - off] : 0;
        int i1 = t + 256;
        int a1 = (i1 >= off) ? s[i1 - off] : 0;
        __syncthreads();
        s[t] += a0; s[i1] += a1;
        __syncthreads();
    }
#pragma unroll
    for (int k = 0; k < 2; ++k) {
        int i = t + k * 256;
        int excl = s[i] - h[i];
        cur[i] = excl;
        int node = (b << PB_SHIFT) + i;
        if (node < N) offs[node] = beg + excl;
    }
    if (b == 0 && t == 0) offs[N] = E;
    __syncthreads();
    for (int e = beg + t; e < end; e += 256) {
        int2 sd = part[e];
        int p = atomicAdd(&cur[sd.y & 511], 1);
        ssrc[beg + p] = sd.x;
    }
}

// ---------------------------------------------------------------------------
// MFMA GEMM: A[M][128] @ [Wl;Wr][dout][128].T
//   AT = float (layer 0, converted during staging) or __bf16.
//   ZT = __bf16 (LN layers) or float (final layer). y always bf16.
// 64x64 block tile, 4 waves 2x2, K=128 LDS-resident (stride 136 bf16).
// ---------------------------------------------------------------------------
template <typename AT, typename ZT>
__global__ __launch_bounds__(256) void gemm_mfma(
    const AT* __restrict__ A,
    const float* __restrict__ Wl,
    const float* __restrict__ Wr,
    const float* __restrict__ bias,
    __bf16* __restrict__ ybuf,
    ZT*     __restrict__ zbuf,
    int M, int dout) {
    __shared__ __bf16 Asm[64 * 136];
    __shared__ __bf16 Bsm[64 * 136];

    const int t = threadIdx.x;
    const int rowBase = blockIdx.x * 64;
    const int by = blockIdx.y;
    const int nyHalf = dout >> 6;
    const bool isZ = by >= nyHalf;
    const float* W = isZ ? Wr : Wl;
    const int colLocal = (by - (isZ ? nyHalf : 0)) * 64;

    if constexpr (sizeof(AT) == 4) {
        // fp32 A: 2048 float4 chunks, convert to bf16 while staging.
#pragma unroll
        for (int i = 0; i < 8; ++i) {
            int idx = t + 256 * i;
            int r = idx >> 5;
            int c4 = idx & 31;
            int grow = rowBase + r;
            if (grow >= M) grow = M - 1;
            float4 v = *(const float4*)((const float*)A + (size_t)grow * 128 + c4 * 4);
            bf16x4 o;
            o[0] = (__bf16)v.x; o[1] = (__bf16)v.y; o[2] = (__bf16)v.z; o[3] = (__bf16)v.w;
            *(bf16x4*)(Asm + r * 136 + c4 * 4) = o;
        }
    } else {
#pragma unroll
        for (int i = 0; i < 4; ++i) {
            int idx = t + 256 * i;
            int r = idx >> 4;
            int c8 = idx & 15;
            int grow = rowBase + r;
            if (grow >= M) grow = M - 1;
            bf16x8 v = *(const bf16x8*)((const __bf16*)A + (size_t)grow * 128 + c8 * 8);
            *(bf16x8*)(Asm + r * 136 + c8 * 8) = v;
        }
    }
#pragma unroll
    for (int i = 0; i < 8; ++i) {
        int idx = t + 256 * i;
        int r = idx >> 5;
        int c4 = idx & 31;
        float4 v = *(const float4*)(W + (size_t)(colLocal + r) * 128 + c4 * 4);
        bf16x4 o;
        o[0] = (__bf16)v.x; o[1] = (__bf16)v.y; o[2] = (__bf16)v.z; o[3] = (__bf16)v.w;
        *(bf16x4*)(Bsm + r * 136 + c4 * 4) = o;
    }
    __syncthreads();

    const int lane = t & 63;
    const int wid = t >> 6;
    const int mb = (wid >> 1) * 32;
    const int nb = (wid & 1) * 32;
    const int ln = lane & 15;
    const int qk = lane >> 4;

    f32x4 acc[2][2] = {};
#pragma unroll
    for (int ks = 0; ks < 4; ++ks) {
        const int k0 = ks * 32 + qk * 8;
        bf16x8 a0 = *(const bf16x8*)(Asm + (mb + ln) * 136 + k0);
        bf16x8 a1 = *(const bf16x8*)(Asm + (mb + 16 + ln) * 136 + k0);
        bf16x8 b0 = *(const bf16x8*)(Bsm + (nb + ln) * 136 + k0);
        bf16x8 b1 = *(const bf16x8*)(Bsm + (nb + 16 + ln) * 136 + k0);
        acc[0][0] = __builtin_amdgcn_mfma_f32_16x16x32_bf16(a0, b0, acc[0][0], 0, 0, 0);
        acc[0][1] = __builtin_amdgcn_mfma_f32_16x16x32_bf16(a0, b1, acc[0][1], 0, 0, 0);
        acc[1][0] = __builtin_amdgcn_mfma_f32_16x16x32_bf16(a1, b0, acc[1][0], 0, 0, 0);
        acc[1][1] = __builtin_amdgcn_mfma_f32_16x16x32_bf16(a1, b1, acc[1][1], 0, 0, 0);
    }

    // C/D: col = lane&15, row = (lane>>4)*4 + reg  [m89-verified]
#pragma unroll
    for (int i = 0; i < 2; ++i) {
#pragma unroll
        for (int r = 0; r < 4; ++r) {
            int grow = rowBase + mb + i * 16 + qk * 4 + r;
            if (grow >= M) continue;
#pragma unroll
            for (int j = 0; j < 2; ++j) {
                int col = colLocal + nb + j * 16 + ln;
                float v = acc[i][j][r];
                if (isZ) zbuf[(size_t)grow * dout + col] = (ZT)(v + bias[col]);
                else     ybuf[(size_t)grow * dout + col] = (__bf16)v;
            }
        }
    }
}

// ---------------------------------------------------------------------------
// Aggregation 128f: wave/node; 4 edges per iter (lane quads read 16B bf16x8).
// mean(y bf16) + z(bf16) -> ReLU -> LN -> h (bf16).
// ---------------------------------------------------------------------------
__global__ __launch_bounds__(256) void agg_ln128(
    const int* __restrict__ offs, const int* __restrict__ ssrc,
    const __bf16* __restrict__ ybuf,   // [N][128]
    const __bf16* __restrict__ zbuf,   // [N][128]
    const float* __restrict__ gamma, const float* __restrict__ beta,
    __bf16* __restrict__ hout, int nNodes) {
    const int lane = threadIdx.x & 63;
    const int qh = lane >> 4;
    const int li = lane & 15;
    const int node = blockIdx.x * 4 + (threadIdx.x >> 6);
    if (node >= nNodes) return;
    const int beg = offs[node], end = offs[node + 1];

    float acc[8] = {};
    for (int j = beg; j < end; j += 64) {
        int cnt = end - j;
        if (cnt > 64) cnt = 64;
        int sidx = ssrc[j + ((lane < cnt) ? lane : 0)];
        int quads = (cnt + 3) >> 2;
        for (int u = 0; u < quads; ++u) {
            int e = 4 * u + qh;
            int s = __shfl(sidx, (e < cnt) ? e : 0, 64);
            if (e < cnt) {
                bf16x8 v = *(const bf16x8*)(ybuf + (size_t)s * 128 + li * 8);
#pragma unroll
                for (int m = 0; m < 8; ++m) acc[m] += (float)v[m];
            }
        }
    }
#pragma unroll
    for (int m = 0; m < 8; ++m) {
        acc[m] += __shfl_xor(acc[m], 16, 64);
        acc[m] += __shfl_xor(acc[m], 32, 64);
    }
    int degn = end - beg;
    float inv = 1.f / (float)((degn > 1) ? degn : 1);
    bf16x8 zv = *(const bf16x8*)(zbuf + (size_t)node * 128 + li * 8);
    float v[8];
#pragma unroll
    for (int m = 0; m < 8; ++m) v[m] = fmaxf(acc[m] * inv + (float)zv[m], 0.f);

    float s = 0.f;
#pragma unroll
    for (int m = 0; m < 8; ++m) s += v[m];
#pragma unroll
    for (int off = 8; off >= 1; off >>= 1) s += __shfl_xor(s, off, 64);
    float mu = s * (1.f / 128.f);
    float d[8], q = 0.f;
#pragma unroll
    for (int m = 0; m < 8; ++m) { d[m] = v[m] - mu; q += d[m] * d[m]; }
#pragma unroll
    for (int off = 8; off >= 1; off >>= 1) q += __shfl_xor(q, off, 64);
    float rstd = rsqrtf(q * (1.f / 128.f) + 1e-5f);

    if (qh == 0) {
        const float4* g4 = (const float4*)(gamma + li * 8);
        const float4* b4 = (const float4*)(beta + li * 8);
        float4 g0 = g4[0], g1 = g4[1], bb0 = b4[0], bb1 = b4[1];
        bf16x8 o;
        o[0] = (__bf16)(d[0] * rstd * g0.x + bb0.x);
        o[1] = (__bf16)(d[1] * rstd * g0.y + bb0.y);
        o[2] = (__bf16)(d[2] * rstd * g0.z + bb0.z);
        o[3] = (__bf16)(d[3] * rstd * g0.w + bb0.w);
        o[4] = (__bf16)(d[4] * rstd * g1.x + bb1.x);
        o[5] = (__bf16)(d[5] * rstd * g1.y + bb1.y);
        o[6] = (__bf16)(d[6] * rstd * g1.z + bb1.z);
        o[7] = (__bf16)(d[7] * rstd * g1.w + bb1.w);
        *(bf16x8*)(hout + (size_t)node * 128 + li * 8) = o;
    }
}

// Aggregation 64f (final): 8 edges per iter; mean(y bf16) + z(fp32) -> out fp32.
__global__ __launch_bounds__(256) void agg_out64(
    const int* __restrict__ offs, const int* __restrict__ ssrc,
    const __bf16* __restrict__ ybuf,   // [N][64]
    const float* __restrict__ zbuf,    // [N][64]
    float* __restrict__ out, int nNodes) {
    const int lane = threadIdx.x & 63;
    const int eh = lane >> 3;
    const int li = lane & 7;
    const int node = blockIdx.x * 4 + (threadIdx.x >> 6);
    if (node >= nNodes) return;
    const int beg = offs[node], end = offs[node + 1];

    float acc[8] = {};
    for (int j = beg; j < end; j += 64) {
        int cnt = end - j;
        if (cnt > 64) cnt = 64;
        int sidx = ssrc[j + ((lane < cnt) ? lane : 0)];
        int octs = (cnt + 7) >> 3;
        for (int u = 0; u < octs; ++u) {
            int e = 8 * u + eh;
            int s = __shfl(sidx, (e < cnt) ? e : 0, 64);
            if (e < cnt) {
                bf16x8 v = *(const bf16x8*)(ybuf + (size_t)s * 64 + li * 8);
#pragma unroll
                for (int m = 0; m < 8; ++m) acc[m] += (float)v[m];
            }
        }
    }
#pragma unroll
    for (int m = 0; m < 8; ++m) {
        acc[m] += __shfl_xor(acc[m], 8, 64);
        acc[m] += __shfl_xor(acc[m], 16, 64);
        acc[m] += __shfl_xor(acc[m], 32, 64);
    }
    if (eh == 0) {
        int degn = end - beg;
        float inv = 1.f / (float)((degn > 1) ? degn : 1);
        const float4* z4 = (const float4*)(zbuf + (size_t)node * 64 + li * 8);
        float4 z0 = z4[0], z1 = z4[1];
        float4 o0, o1;
        o0.x = acc[0] * inv + z0.x;
        o0.y = acc[1] * inv + z0.y;
        o0.z = acc[2] * inv + z0.z;
        o0.w = acc[3] * inv + z0.w;
        o1.x = acc[4] * inv + z1.x;
        o1.y = acc[5] * inv + z1.y;
        o1.z = acc[6] * inv + z1.z;
        o1.w = acc[7] * inv + z1.w;
        float4* op = (float4*)(out + (size_t)node * 64 + li * 8);
        op[0] = o0;
        op[1] = o1;
    }
}

// ---------------------------------------------------------------------------
extern "C" void kernel_launch(void* const* d_in, const int* in_sizes, int n_in,
                              void* d_out, int out_size, void* d_ws, size_t ws_size,
                              hipStream_t stream) {
    const float* x   = (const float*)d_in[0];
    const int*   ei  = (const int*)d_in[1];
    const float* Wl0 = (const float*)d_in[2];
    const float* Wr0 = (const float*)d_in[3];
    const float* b0  = (const float*)d_in[4];
    const float* Wl1 = (const float*)d_in[5];
    const float* Wr1 = (const float*)d_in[6];
    const float* b1  = (const float*)d_in[7];
    const float* Wl2 = (const float*)d_in[8];
    const float* Wr2 = (const float*)d_in[9];
    const float* b2  = (const float*)d_in[10];
    const float* g0  = (const float*)d_in[11];
    const float* be0 = (const float*)d_in[12];
    const float* g1  = (const float*)d_in[13];
    const float* be1 = (const float*)d_in[14];

    const int N = in_sizes[0] / 128;
    const int E = in_sizes[1] / 2;
    const int* src = ei;
    const int* dst = ei + E;
    float* out = (float*)d_out;

    char* p = (char*)d_ws;
    auto carve = [&](size_t bytes) {
        void* q = (void*)p;
        p += (bytes + 255) & ~(size_t)255;
        return q;
    };
    int*     offs  = (int*)carve(sizeof(int) * (size_t)(N + 1));
    int*     bhist = (int*)carve(sizeof(int) * (size_t)PB_NB);
    int*     bbase = (int*)carve(sizeof(int) * (size_t)PB_NB);
    int*     bcur  = (int*)carve(sizeof(int) * (size_t)PB_NB);
    int*     ssrc  = (int*)carve(sizeof(int) * (size_t)E);
    int2*    part  = (int2*)carve(sizeof(int2) * (size_t)E);
    __bf16*  h     = (__bf16*)carve(sizeof(__bf16) * (size_t)N * 128);
    __bf16*  ybuf  = (__bf16*)carve(sizeof(__bf16) * (size_t)N * 128);
    void*    zraw  = carve(sizeof(__bf16) * (size_t)N * 128);  // 25.6MB, aliased
    __bf16*  zb    = (__bf16*)zraw;   // LN layers: [N][128] bf16
    float*   zf    = (float*)zraw;    // final layer: [N][64] fp32

    // --- CSR build ---
    hipMemsetAsync(bhist, 0, sizeof(int) * PB_NB, stream);
    const int gridE = (E + PB_CHUNK - 1) / PB_CHUNK;
    coarse_hist<<<gridE, PB_BLOCK, 0, stream>>>(dst, bhist, E);
    coarse_scan<<<1, PB_NB, 0, stream>>>(bhist, bbase, bcur);
    part_scatter<<<gridE, PB_BLOCK, 0, stream>>>(src, dst, bcur, part, E);
    bucket_build<<<PB_NB, 256, 0, stream>>>(part, bbase, offs, ssrc, N, E);

    const int gridM = (N + 63) / 64;
    const int gridNode = (N + 3) / 4;

    // --- Layer 0 (A fp32, converted in staging) ---
    gemm_mfma<float, __bf16><<<dim3(gridM, 4), 256, 0, stream>>>(x, Wl0, Wr0, b0, ybuf, zb, N, 128);
    agg_ln128<<<gridNode, 256, 0, stream>>>(offs, ssrc, ybuf, zb, g0, be0, h, N);
    // --- Layer 1 ---
    gemm_mfma<__bf16, __bf16><<<dim3(gridM, 4), 256, 0, stream>>>(h, Wl1, Wr1, b1, ybuf, zb, N, 128);
    agg_ln128<<<gridNode, 256, 0, stream>>>(offs, ssrc, ybuf, zb, g1, be1, h, N);
    // --- Layer 2 (64 feats, z fp32, no LN/ReLU) ---
    gemm_mfma<__bf16, float><<<dim3(gridM, 2), 256, 0, stream>>>(h, Wl2, Wr2, b2, ybuf, zf, N, 64);
    agg_out64<<<gridNode, 256, 0, stream>>>(offs, ssrc, ybuf, zf, out, N);
}

// Round 7
// 424.972 us; speedup vs baseline: 23.3886x; 1.0715x over previous
//
#include <hip/hip_runtime.h>

// ---------------------------------------------------------------------------
// GraphSAGE 3-layer forward, MI355X.
//   CSR build: coarse 256-bucket histogram -> tiny scan -> part_scatter
//     (bucket-grouped int2 edges, dense writes) -> bucket_build (per-bucket
//     LDS count/scan/scatter -> offs + ssrc). No node-level global atomics.
//   Per layer: bf16 MFMA GEMM [y|z] = A @ [Wl;Wr].T (fp32 accum), 64x128
//     tiles (A staged twice per layer, not 4x); y bf16; z bf16 (LN layers)
//     or fp32 (final); layer-0 A converted fp32->bf16 during staging.
//   Aggregation: per-quad direct index loads w/ 1-iter prefetch (no shfl),
//     gather-mean + z + ReLU + LayerNorm -> h (bf16).
// R6->R7: agg inner loop dropped ds_bpermute chain; gemm 64x128 tiles.
// ---------------------------------------------------------------------------

typedef __bf16 bf16x8 __attribute__((ext_vector_type(8)));
typedef __bf16 bf16x4 __attribute__((ext_vector_type(4)));
typedef float  f32x4  __attribute__((ext_vector_type(4)));

#define PB_SHIFT 9                      // 512 nodes per coarse bucket
#define PB_NB    256                    // covers N <= 131072
#define PB_EPT   8
#define PB_BLOCK 256
#define PB_CHUNK (PB_BLOCK * PB_EPT)    // 2048 edges per block

__global__ __launch_bounds__(PB_BLOCK) void coarse_hist(
    const int* __restrict__ dst, int* __restrict__ bhist, int E) {
    __shared__ int h[PB_NB];
    const int t = threadIdx.x;
    h[t] = 0;
    __syncthreads();
    const int e0 = blockIdx.x * PB_CHUNK + t;
#pragma unroll
    for (int i = 0; i < PB_EPT; ++i) {
        int e = e0 + i * PB_BLOCK;
        if (e < E) atomicAdd(&h[dst[e] >> PB_SHIFT], 1);
    }
    __syncthreads();
    if (h[t]) atomicAdd(&bhist[t], h[t]);
}

__global__ __launch_bounds__(PB_NB) void coarse_scan(
    const int* __restrict__ bhist, int* __restrict__ bbase, int* __restrict__ bcur) {
    __shared__ int sm[PB_NB];
    const int t = threadIdx.x;
    int v = bhist[t];
    sm[t] = v;
    __syncthreads();
    for (int off = 1; off < PB_NB; off <<= 1) {
        int add = (t >= off) ? sm[t - off] : 0;
        __syncthreads();
        sm[t] += add;
        __syncthreads();
    }
    int excl = sm[t] - v;
    bbase[t] = excl;
    bcur[t] = excl;
}

__global__ __launch_bounds__(PB_BLOCK) void part_scatter(
    const int* __restrict__ src, const int* __restrict__ dst,
    int* __restrict__ bcursor, int2* __restrict__ part, int E) {
    __shared__ int hist[PB_NB];
    __shared__ int base[PB_NB];
    const int t = threadIdx.x;
    hist[t] = 0;
    __syncthreads();
    const int e0 = blockIdx.x * PB_CHUNK + t;
    int my_s[PB_EPT], my_d[PB_EPT], my_r[PB_EPT];
#pragma unroll
    for (int i = 0; i < PB_EPT; ++i) {
        int e = e0 + i * PB_BLOCK;
        if (e < E) {
            my_s[i] = src[e];
            my_d[i] = dst[e];
            my_r[i] = atomicAdd(&hist[my_d[i] >> PB_SHIFT], 1);
        }
    }
    __syncthreads();
    {
        int c = hist[t];
        base[t] = c ? atomicAdd(&bcursor[t], c) : 0;
    }
    __syncthreads();
#pragma unroll
    for (int i = 0; i < PB_EPT; ++i) {
        int e = e0 + i * PB_BLOCK;
        if (e < E) {
            int b = my_d[i] >> PB_SHIFT;
            part[base[b] + my_r[i]] = make_int2(my_s[i], my_d[i]);
        }
    }
}

__global__ __launch_bounds__(256) void bucket_build(
    const int2* __restrict__ part, const int* __restrict__ bbase,
    int* __restrict__ offs, int* __restrict__ ssrc, int N, int E) {
    __shared__ int h[512];
    __shared__ int s[512];
    __shared__ int cur[512];
    const int b = blockIdx.x;
    const int t = threadIdx.x;
    const int beg = bbase[b];
    const int end = (b == PB_NB - 1) ? E : bbase[b + 1];

    h[t] = 0; h[t + 256] = 0;
    __syncthreads();
    for (int e = beg + t; e < end; e += 256)
        atomicAdd(&h[part[e].y & 511], 1);
    __syncthreads();
    s[t] = h[t]; s[t + 256] = h[t + 256];
    __syncthreads();
    for (int off = 1; off < 512; off <<= 1) {
        int a0 = (t >= off) ? s[t - off] : 0;
        int i1 = t + 256;
        int a1 = (i1 >= off) ? s[i1 - off] : 0;
        __syncthreads();
        s[t] += a0; s[i1] += a1;
        __syncthreads();
    }
#pragma unroll
    for (int k = 0; k < 2; ++k) {
        int i = t + k * 256;
        int excl = s[i] - h[i];
        cur[i] = excl;
        int node = (b << PB_SHIFT) + i;
        if (node < N) offs[node] = beg + excl;
    }
    if (b == 0 && t == 0) offs[N] = E;
    __syncthreads();
    for (int e = beg + t; e < end; e += 256) {
        int2 sd = part[e];
        int p = atomicAdd(&cur[sd.y & 511], 1);
        ssrc[beg + p] = sd.x;
    }
}

// ---------------------------------------------------------------------------
// MFMA GEMM: out cols = full DOUT of Wl (by=0 -> ybuf bf16) or Wr (by=1 ->
// zbuf + bias). 64 rows x DOUT cols per block, 4 waves each 32 x DOUT/2.
// K=128 LDS-resident (stride 136 bf16 -> 2-way aliasing, free).
// ---------------------------------------------------------------------------
template <int DOUT, typename AT, typename ZT>
__global__ __launch_bounds__(256) void gemm_mfma(
    const AT* __restrict__ A,
    const float* __restrict__ Wl,
    const float* __restrict__ Wr,
    const float* __restrict__ bias,
    __bf16* __restrict__ ybuf,
    ZT*     __restrict__ zbuf,
    int M) {
    __shared__ __bf16 Asm[64 * 136];
    __shared__ __bf16 Bsm[DOUT * 136];

    const int t = threadIdx.x;
    const int rowBase = blockIdx.x * 64;
    const bool isZ = blockIdx.y != 0;
    const float* W = isZ ? Wr : Wl;

    if constexpr (sizeof(AT) == 4) {
#pragma unroll
        for (int i = 0; i < 8; ++i) {
            int idx = t + 256 * i;
            int r = idx >> 5;
            int c4 = idx & 31;
            int grow = rowBase + r;
            if (grow >= M) grow = M - 1;
            float4 v = *(const float4*)((const float*)A + (size_t)grow * 128 + c4 * 4);
            bf16x4 o;
            o[0] = (__bf16)v.x; o[1] = (__bf16)v.y; o[2] = (__bf16)v.z; o[3] = (__bf16)v.w;
            *(bf16x4*)(Asm + r * 136 + c4 * 4) = o;
        }
    } else {
#pragma unroll
        for (int i = 0; i < 4; ++i) {
            int idx = t + 256 * i;
            int r = idx >> 4;
            int c8 = idx & 15;
            int grow = rowBase + r;
            if (grow >= M) grow = M - 1;
            bf16x8 v = *(const bf16x8*)((const __bf16*)A + (size_t)grow * 128 + c8 * 8);
            *(bf16x8*)(Asm + r * 136 + c8 * 8) = v;
        }
    }
    constexpr int BCH = DOUT * 32 / 256;   // float4 chunks per thread
#pragma unroll
    for (int i = 0; i < BCH; ++i) {
        int idx = t + 256 * i;
        int r = idx >> 5;
        int c4 = idx & 31;
        float4 v = *(const float4*)(W + (size_t)r * 128 + c4 * 4);
        bf16x4 o;
        o[0] = (__bf16)v.x; o[1] = (__bf16)v.y; o[2] = (__bf16)v.z; o[3] = (__bf16)v.w;
        *(bf16x4*)(Bsm + r * 136 + c4 * 4) = o;
    }
    __syncthreads();

    const int lane = t & 63;
    const int wid = t >> 6;
    const int mb = (wid >> 1) * 32;              // row half
    const int nbase = (wid & 1) * (DOUT / 2);    // col half
    constexpr int NJ = DOUT / 32;                // 16-col tiles per wave
    const int ln = lane & 15;
    const int qk = lane >> 4;

    f32x4 acc[2][NJ] = {};
#pragma unroll
    for (int ks = 0; ks < 4; ++ks) {
        const int k0 = ks * 32 + qk * 8;
        bf16x8 a0 = *(const bf16x8*)(Asm + (mb + ln) * 136 + k0);
        bf16x8 a1 = *(const bf16x8*)(Asm + (mb + 16 + ln) * 136 + k0);
        bf16x8 b[NJ];
#pragma unroll
        for (int j = 0; j < NJ; ++j)
            b[j] = *(const bf16x8*)(Bsm + (nbase + j * 16 + ln) * 136 + k0);
#pragma unroll
        for (int j = 0; j < NJ; ++j) {
            acc[0][j] = __builtin_amdgcn_mfma_f32_16x16x32_bf16(a0, b[j], acc[0][j], 0, 0, 0);
            acc[1][j] = __builtin_amdgcn_mfma_f32_16x16x32_bf16(a1, b[j], acc[1][j], 0, 0, 0);
        }
    }

    float bcol[NJ];
    if (isZ) {
#pragma unroll
        for (int j = 0; j < NJ; ++j) bcol[j] = bias[nbase + j * 16 + ln];
    }
    // C/D: col = lane&15, row = (lane>>4)*4 + reg  [m89-verified]
#pragma unroll
    for (int i = 0; i < 2; ++i) {
#pragma unroll
        for (int r = 0; r < 4; ++r) {
            int grow = rowBase + mb + i * 16 + qk * 4 + r;
            if (grow >= M) continue;
#pragma unroll
            for (int j = 0; j < NJ; ++j) {
                int col = nbase + j * 16 + ln;
                float v = acc[i][j][r];
                if (isZ) zbuf[(size_t)grow * DOUT + col] = (ZT)(v + bcol[j]);
                else     ybuf[(size_t)grow * DOUT + col] = (__bf16)v;
            }
        }
    }
}

// ---------------------------------------------------------------------------
// Aggregation 128f: one wave per node; 16-lane quads each handle one edge per
// iter, loading the edge index directly (broadcast, L1-hot) with a 1-iter
// prefetch. mean(y bf16) + z(bf16) -> ReLU -> LN -> h (bf16).
// ---------------------------------------------------------------------------
__global__ __launch_bounds__(256) void agg_ln128(
    const int* __restrict__ offs, const int* __restrict__ ssrc,
    const __bf16* __restrict__ ybuf,   // [N][128]
    const __bf16* __restrict__ zbuf,   // [N][128]
    const float* __restrict__ gamma, const float* __restrict__ beta,
    __bf16* __restrict__ hout, int nNodes) {
    const int lane = threadIdx.x & 63;
    const int qh = lane >> 4;
    const int li = lane & 15;
    const int node = blockIdx.x * 4 + (threadIdx.x >> 6);
    if (node >= nNodes) return;
    const int beg = offs[node], end = offs[node + 1];
    const int deg = end - beg;

    float acc[8] = {};
    const int iters = (deg + 3) >> 2;
    int e = beg + qh;
    int idx = 0;
    if (iters > 0) idx = ssrc[(e < end) ? e : beg];
    for (int u = 0; u < iters; ++u) {
        int en = e + 4;
        int idxN = ssrc[(en < end) ? en : beg];   // prefetch next
        if (e < end) {
            uint4 uv = *(const uint4*)(ybuf + (size_t)idx * 128 + li * 8);
            acc[0] += __uint_as_float(uv.x << 16);
            acc[1] += __uint_as_float(uv.x & 0xffff0000u);
            acc[2] += __uint_as_float(uv.y << 16);
            acc[3] += __uint_as_float(uv.y & 0xffff0000u);
            acc[4] += __uint_as_float(uv.z << 16);
            acc[5] += __uint_as_float(uv.z & 0xffff0000u);
            acc[6] += __uint_as_float(uv.w << 16);
            acc[7] += __uint_as_float(uv.w & 0xffff0000u);
        }
        e = en; idx = idxN;
    }
#pragma unroll
    for (int m = 0; m < 8; ++m) {
        acc[m] += __shfl_xor(acc[m], 16, 64);
        acc[m] += __shfl_xor(acc[m], 32, 64);
    }
    float inv = 1.f / (float)((deg > 1) ? deg : 1);
    bf16x8 zv = *(const bf16x8*)(zbuf + (size_t)node * 128 + li * 8);
    float v[8];
#pragma unroll
    for (int m = 0; m < 8; ++m) v[m] = fmaxf(acc[m] * inv + (float)zv[m], 0.f);

    float s = 0.f;
#pragma unroll
    for (int m = 0; m < 8; ++m) s += v[m];
#pragma unroll
    for (int off = 8; off >= 1; off >>= 1) s += __shfl_xor(s, off, 64);
    float mu = s * (1.f / 128.f);
    float d[8], q = 0.f;
#pragma unroll
    for (int m = 0; m < 8; ++m) { d[m] = v[m] - mu; q += d[m] * d[m]; }
#pragma unroll
    for (int off = 8; off >= 1; off >>= 1) q += __shfl_xor(q, off, 64);
    float rstd = rsqrtf(q * (1.f / 128.f) + 1e-5f);

    if (qh == 0) {
        const float4* g4 = (const float4*)(gamma + li * 8);
        const float4* b4 = (const float4*)(beta + li * 8);
        float4 g0 = g4[0], g1 = g4[1], bb0 = b4[0], bb1 = b4[1];
        bf16x8 o;
        o[0] = (__bf16)(d[0] * rstd * g0.x + bb0.x);
        o[1] = (__bf16)(d[1] * rstd * g0.y + bb0.y);
        o[2] = (__bf16)(d[2] * rstd * g0.z + bb0.z);
        o[3] = (__bf16)(d[3] * rstd * g0.w + bb0.w);
        o[4] = (__bf16)(d[4] * rstd * g1.x + bb1.x);
        o[5] = (__bf16)(d[5] * rstd * g1.y + bb1.y);
        o[6] = (__bf16)(d[6] * rstd * g1.z + bb1.z);
        o[7] = (__bf16)(d[7] * rstd * g1.w + bb1.w);
        *(bf16x8*)(hout + (size_t)node * 128 + li * 8) = o;
    }
}

// Aggregation 64f (final): 8-lane groups each handle one edge per iter
// (direct idx load + prefetch); mean(y bf16) + z(fp32) -> out fp32.
__global__ __launch_bounds__(256) void agg_out64(
    const int* __restrict__ offs, const int* __restrict__ ssrc,
    const __bf16* __restrict__ ybuf,   // [N][64]
    const float* __restrict__ zbuf,    // [N][64]
    float* __restrict__ out, int nNodes) {
    const int lane = threadIdx.x & 63;
    const int eh = lane >> 3;
    const int li = lane & 7;
    const int node = blockIdx.x * 4 + (threadIdx.x >> 6);
    if (node >= nNodes) return;
    const int beg = offs[node], end = offs[node + 1];
    const int deg = end - beg;

    float acc[8] = {};
    const int iters = (deg + 7) >> 3;
    int e = beg + eh;
    int idx = 0;
    if (iters > 0) idx = ssrc[(e < end) ? e : beg];
    for (int u = 0; u < iters; ++u) {
        int en = e + 8;
        int idxN = ssrc[(en < end) ? en : beg];
        if (e < end) {
            uint4 uv = *(const uint4*)(ybuf + (size_t)idx * 64 + li * 8);
            acc[0] += __uint_as_float(uv.x << 16);
            acc[1] += __uint_as_float(uv.x & 0xffff0000u);
            acc[2] += __uint_as_float(uv.y << 16);
            acc[3] += __uint_as_float(uv.y & 0xffff0000u);
            acc[4] += __uint_as_float(uv.z << 16);
            acc[5] += __uint_as_float(uv.z & 0xffff0000u);
            acc[6] += __uint_as_float(uv.w << 16);
            acc[7] += __uint_as_float(uv.w & 0xffff0000u);
        }
        e = en; idx = idxN;
    }
#pragma unroll
    for (int m = 0; m < 8; ++m) {
        acc[m] += __shfl_xor(acc[m], 8, 64);
        acc[m] += __shfl_xor(acc[m], 16, 64);
        acc[m] += __shfl_xor(acc[m], 32, 64);
    }
    if (eh == 0) {
        float inv = 1.f / (float)((deg > 1) ? deg : 1);
        const float4* z4 = (const float4*)(zbuf + (size_t)node * 64 + li * 8);
        float4 z0 = z4[0], z1 = z4[1];
        float4 o0, o1;
        o0.x = acc[0] * inv + z0.x;
        o0.y = acc[1] * inv + z0.y;
        o0.z = acc[2] * inv + z0.z;
        o0.w = acc[3] * inv + z0.w;
        o1.x = acc[4] * inv + z1.x;
        o1.y = acc[5] * inv + z1.y;
        o1.z = acc[6] * inv + z1.z;
        o1.w = acc[7] * inv + z1.w;
        float4* op = (float4*)(out + (size_t)node * 64 + li * 8);
        op[0] = o0;
        op[1] = o1;
    }
}

// ---------------------------------------------------------------------------
extern "C" void kernel_launch(void* const* d_in, const int* in_sizes, int n_in,
                              void* d_out, int out_size, void* d_ws, size_t ws_size,
                              hipStream_t stream) {
    const float* x   = (const float*)d_in[0];
    const int*   ei  = (const int*)d_in[1];
    const float* Wl0 = (const float*)d_in[2];
    const float* Wr0 = (const float*)d_in[3];
    const float* b0  = (const float*)d_in[4];
    const float* Wl1 = (const float*)d_in[5];
    const float* Wr1 = (const float*)d_in[6];
    const float* b1  = (const float*)d_in[7];
    const float* Wl2 = (const float*)d_in[8];
    const float* Wr2 = (const float*)d_in[9];
    const float* b2  = (const float*)d_in[10];
    const float* g0  = (const float*)d_in[11];
    const float* be0 = (const float*)d_in[12];
    const float* g1  = (const float*)d_in[13];
    const float* be1 = (const float*)d_in[14];

    const int N = in_sizes[0] / 128;
    const int E = in_sizes[1] / 2;
    const int* src = ei;
    const int* dst = ei + E;
    float* out = (float*)d_out;

    char* p = (char*)d_ws;
    auto carve = [&](size_t bytes) {
        void* q = (void*)p;
        p += (bytes + 255) & ~(size_t)255;
        return q;
    };
    int*     offs  = (int*)carve(sizeof(int) * (size_t)(N + 1));
    int*     bhist = (int*)carve(sizeof(int) * (size_t)PB_NB);
    int*     bbase = (int*)carve(sizeof(int) * (size_t)PB_NB);
    int*     bcur  = (int*)carve(sizeof(int) * (size_t)PB_NB);
    int*     ssrc  = (int*)carve(sizeof(int) * (size_t)E);
    int2*    part  = (int2*)carve(sizeof(int2) * (size_t)E);
    __bf16*  h     = (__bf16*)carve(sizeof(__bf16) * (size_t)N * 128);
    __bf16*  ybuf  = (__bf16*)carve(sizeof(__bf16) * (size_t)N * 128);
    void*    zraw  = carve(sizeof(__bf16) * (size_t)N * 128);  // aliased
    __bf16*  zb    = (__bf16*)zraw;   // LN layers: [N][128] bf16
    float*   zf    = (float*)zraw;    // final layer: [N][64] fp32

    // --- CSR build ---
    hipMemsetAsync(bhist, 0, sizeof(int) * PB_NB, stream);
    const int gridE = (E + PB_CHUNK - 1) / PB_CHUNK;
    coarse_hist<<<gridE, PB_BLOCK, 0, stream>>>(dst, bhist, E);
    coarse_scan<<<1, PB_NB, 0, stream>>>(bhist, bbase, bcur);
    part_scatter<<<gridE, PB_BLOCK, 0, stream>>>(src, dst, bcur, part, E);
    bucket_build<<<PB_NB, 256, 0, stream>>>(part, bbase, offs, ssrc, N, E);

    const int gridM = (N + 63) / 64;
    const int gridNode = (N + 3) / 4;

    // --- Layer 0 (A fp32, converted in staging) ---
    gemm_mfma<128, float, __bf16><<<dim3(gridM, 2), 256, 0, stream>>>(x, Wl0, Wr0, b0, ybuf, zb, N);
    agg_ln128<<<gridNode, 256, 0, stream>>>(offs, ssrc, ybuf, zb, g0, be0, h, N);
    // --- Layer 1 ---
    gemm_mfma<128, __bf16, __bf16><<<dim3(gridM, 2), 256, 0, stream>>>(h, Wl1, Wr1, b1, ybuf, zb, N);
    agg_ln128<<<gridNode, 256, 0, stream>>>(offs, ssrc, ybuf, zb, g1, be1, h, N);
    // --- Layer 2 (64 feats, z fp32, no LN/ReLU) ---
    gemm_mfma<64, __bf16, float><<<dim3(gridM, 2), 256, 0, stream>>>(h, Wl2, Wr2, b2, ybuf, zf, N);
    agg_out64<<<gridNode, 256, 0, stream>>>(offs, ssrc, ybuf, zf, out, N);
}